// Round 9
// baseline (463.740 us; speedup 1.0000x reference)
//
#include <hip/hip_runtime.h>
#include <math.h>

#define LOG2PI 1.8378770664093453f

// Problem sizes (fixed)
#define NB 32
#define NT 1024
#define ND 512
#define NH 512
#define NX 32
#define NK 8
#define NU 2

// chunked scan: 1023 transitions = 93 chunks x 11
#define NCH 93
#define CHL 11

typedef __attribute__((ext_vector_type(8))) short bf16x8;
typedef __attribute__((ext_vector_type(4))) float f32x4;

__device__ __forceinline__ unsigned short f2bf(float f) {
    unsigned u = __float_as_uint(f);
    unsigned r = (u + 0x7FFF + ((u >> 16) & 1)) >> 16;
    return (unsigned short)r;
}

// pack two f32 -> two bf16 (round-half-up) in ONE v_perm + 2 adds
__device__ __forceinline__ unsigned pack_bf2(float a, float b) {
    unsigned ua = __float_as_uint(a) + 0x8000u;
    unsigned ub = __float_as_uint(b) + 0x8000u;
    return __builtin_amdgcn_perm(ub, ua, 0x07060302);
}

// fast tanh: 1 - 2/(e^{2x}+1)
__device__ __forceinline__ float tanh_fast(float v) {
    float t = __expf(2.0f * v);
    return 1.0f - 2.0f * __builtin_amdgcn_rcpf(t + 1.0f);
}

// ---------------------------------------------------------------------------
// DPP xor-shuffles within 8-lane groups
// ---------------------------------------------------------------------------
#define DPP_X1 0xB1
#define DPP_X2 0x4E
#define DPP_X3 0x1B
#define DPP_X7 0x141

template <int CTRL>
__device__ __forceinline__ float dppx(float v) {
    return __int_as_float(__builtin_amdgcn_update_dpp(
        0, __float_as_int(v), CTRL, 0xF, 0xF, true));
}

__device__ __forceinline__ float fb_matvec(float4 a0, float4 a1, float v) {
    float p1 = dppx<DPP_X1>(v);
    float p2 = dppx<DPP_X2>(v);
    float p3 = dppx<DPP_X3>(v);
    float p7 = dppx<DPP_X7>(v);
    float p4 = dppx<DPP_X7>(p3);
    float p5 = dppx<DPP_X7>(p2);
    float p6 = dppx<DPP_X7>(p1);
    float c0 = fmaf(a0.y, p1, a0.x * v);
    float c1 = fmaf(a0.w, p3, a0.z * p2);
    float c2 = fmaf(a1.y, p5, a1.x * p4);
    float c3 = fmaf(a1.w, p7, a1.z * p6);
    return (c0 + c1) + (c2 + c3);
}

__device__ __forceinline__ float fb_matvecT(float4 a0, float4 a1, float w) {
    float q0 = a0.x * w;
    float t1 = dppx<DPP_X1>(a0.y * w);
    float t2 = dppx<DPP_X2>(a0.z * w);
    float t3 = dppx<DPP_X3>(a0.w * w);
    float t7 = dppx<DPP_X7>(a1.w * w);
    float t4 = dppx<DPP_X7>(dppx<DPP_X3>(a1.x * w));
    float t5 = dppx<DPP_X7>(dppx<DPP_X2>(a1.y * w));
    float t6 = dppx<DPP_X7>(dppx<DPP_X1>(a1.z * w));
    return ((q0 + t1) + (t2 + t3)) + ((t4 + t5) + (t6 + t7));
}

__device__ __forceinline__ float gsum8(float v) {
    float s = v + dppx<DPP_X1>(v);
    s = s + dppx<DPP_X2>(s);
    s = s + dppx<DPP_X7>(dppx<DPP_X3>(s));
    return s;
}

__device__ __forceinline__ float lse8_high(float v) {
    float m = v;
    m = fmaxf(m, __shfl_xor(m, 8, 64));
    m = fmaxf(m, __shfl_xor(m, 16, 64));
    m = fmaxf(m, __shfl_xor(m, 32, 64));
    float s = __expf(v - m);
    s += __shfl_xor(s, 8, 64);
    s += __shfl_xor(s, 16, 64);
    s += __shfl_xor(s, 32, 64);
    return m + __logf(s);
}

// ---------------------------------------------------------------------------
// K_prep_w: merged weight prep.
//   blocks 0-255   : W1 -> W1T bf16 (32x32 transpose tiles)
//   blocks 256-287 : Wmu/Wlv -> wmlv [64][512] bf16
//   blocks 288-319 : G[x][y] + c2x[x]  (x = bid-288)
//   block  320     : W2bf = bf16(exp(-ylv)*C)
// ---------------------------------------------------------------------------
__global__ __launch_bounds__(256) void k_prep_w(
    const float* __restrict__ W1, const float* __restrict__ Wmu,
    const float* __restrict__ Wlv, const float* __restrict__ C,
    const float* __restrict__ dvec, const float* __restrict__ ylv,
    unsigned short* __restrict__ WT, unsigned short* __restrict__ wmlv,
    unsigned short* __restrict__ W2bf, float* __restrict__ G,
    float* __restrict__ c2x)
{
    __shared__ float tile[32][33];
    const int bid = blockIdx.x;
    const int tid = threadIdx.x;
    if (bid < 256) {
        const int bx = (bid & 15) * 32;   // k-base
        const int by = (bid >> 4) * 32;   // n-base
        const int tx = tid & 31, ty = tid >> 5;
        for (int i = ty; i < 32; i += 8)
            tile[i][tx] = W1[(size_t)(bx + i) * 512 + by + tx];
        __syncthreads();
        for (int i = ty; i < 32; i += 8)
            WT[(size_t)(by + i) * 512 + bx + tx] = f2bf(tile[tx][i]);
        return;
    }
    if (bid < 288) {
        const int t = bid - 256;
        const float* W = (t >> 4) ? Wlv : Wmu;
        const int base = (t >> 4) * 32;
        const int g = t & 15;
        const int tx = tid & 31, ty = tid >> 5;
        for (int i = ty; i < 32; i += 8)
            tile[i][tx] = W[(size_t)(g * 32 + i) * 32 + tx];
        __syncthreads();
        for (int i = ty; i < 32; i += 8)
            wmlv[(size_t)(base + i) * 512 + g * 32 + tx] = f2bf(tile[tx][i]);
        return;
    }
    if (bid == 320) {
        for (int i = tid; i < 32 * 512; i += 256)
            W2bf[i] = f2bf(C[i] * __expf(-ylv[i & 511]));
        return;
    }
    const int x = bid - 288;
    const int y = tid >> 3, seg = tid & 7;
    const float* Cx = &C[(size_t)x * 512];
    const float* Cy = &C[(size_t)y * 512];
    float p = 0.f;
    for (int j = 0; j < 64; ++j) {
        int dcol = seg * 64 + j;
        p = fmaf(Cx[dcol] * __expf(-ylv[dcol]), Cy[dcol], p);
    }
    p = gsum8(p);
    if (seg == 0) G[x * 33 + y] = p;
    if (tid < 8) {
        float q = 0.f;
        for (int j = 0; j < 64; ++j) {
            int dcol = tid * 64 + j;
            q = fmaf(Cx[dcol] * __expf(-ylv[dcol]), dvec[dcol], q);
        }
        q = gsum8(q);
        if (tid == 0) c2x[x] = q;
    }
}

// ---------------------------------------------------------------------------
// K_mlp2: fully fused MLP with RESIDENT A-tile.
// Per 64-row block: stage full-K ysb tile ONCE (f32 read, inline cast, fused
// term1), then proj pass + 4 bn-stages of {h-GEMM -> tanh -> Hs -> mulv}.
// W1T/Wt/W2 B-fragments read global->reg (L1/L2 resident).
// Outputs: x, xent, proj, term1. No h / ysb in HBM.
// ---------------------------------------------------------------------------
__global__ __launch_bounds__(256) void k_mlp2(
    const float* __restrict__ ys,            // [32768][512] f32
    const unsigned short* __restrict__ W1T,  // [512][512] bf16
    const unsigned short* __restrict__ Wt,   // [64][512] bf16 (mu|lv)
    const unsigned short* __restrict__ W2bf, // [32][512] bf16
    const float* __restrict__ b1,
    const float* __restrict__ bmu, const float* __restrict__ blv,
    const float* __restrict__ eps,
    const float* __restrict__ dvec, const float* __restrict__ ylv,
    float* __restrict__ x, float* __restrict__ xent,
    float* __restrict__ proj, float* __restrict__ term1)
{
    __shared__ unsigned short As[64 * 512];  // 64 KB, 16B-slot ^ (row&15)
    __shared__ unsigned short Hs[64 * 128];  // 16 KB, 16B-slot ^ (row&15)
    const int tid = threadIdx.x;
    const int bm = blockIdx.x * 64;
    const int wid = tid >> 6, lane = tid & 63;
    const int l15 = lane & 15, l16 = lane >> 4;

    // per-lane d/iv constants (cols lane*8 .. +8)
    const float4 dv0 = *reinterpret_cast<const float4*>(&dvec[lane * 8]);
    const float4 dv1 = *reinterpret_cast<const float4*>(&dvec[lane * 8 + 4]);
    const float4 yl0 = *reinterpret_cast<const float4*>(&ylv[lane * 8]);
    const float4 yl1 = *reinterpret_cast<const float4*>(&ylv[lane * 8 + 4]);
    float4 iv0, iv1;
    iv0.x = __expf(-yl0.x); iv0.y = __expf(-yl0.y);
    iv0.z = __expf(-yl0.z); iv0.w = __expf(-yl0.w);
    iv1.x = __expf(-yl1.x); iv1.y = __expf(-yl1.y);
    iv1.z = __expf(-yl1.z); iv1.w = __expf(-yl1.w);

    // ---- stage As once: cast f32->bf16, fused term1 ----
#pragma unroll
    for (int r = 0; r < 16; ++r) {
        const int row = r * 4 + wid;
        const float4 f0 = *reinterpret_cast<const float4*>(
            &ys[(size_t)(bm + row) * 512 + lane * 8]);
        const float4 f1 = *reinterpret_cast<const float4*>(
            &ys[(size_t)(bm + row) * 512 + lane * 8 + 4]);
        float g0 = f0.x - dv0.x, g1 = f0.y - dv0.y;
        float g2 = f0.z - dv0.z, g3 = f0.w - dv0.w;
        float g4 = f1.x - dv1.x, g5 = f1.y - dv1.y;
        float g6 = f1.z - dv1.z, g7 = f1.w - dv1.w;
        float t1 = (g0 * g0 * iv0.x + g1 * g1 * iv0.y)
                 + (g2 * g2 * iv0.z + g3 * g3 * iv0.w)
                 + (g4 * g4 * iv1.x + g5 * g5 * iv1.y)
                 + (g6 * g6 * iv1.z + g7 * g7 * iv1.w);
#pragma unroll
        for (int m = 1; m < 64; m <<= 1) t1 += __shfl_xor(t1, m, 64);
        if (lane == 0) term1[bm + row] = t1;
        uint4 ua;
        ua.x = pack_bf2(f0.x, f0.y);
        ua.y = pack_bf2(f0.z, f0.w);
        ua.z = pack_bf2(f1.x, f1.y);
        ua.w = pack_bf2(f1.z, f1.w);
        const int sp = lane ^ (row & 15);
        *reinterpret_cast<uint4*>(&As[row * 512 + sp * 8]) = ua;
    }
    __syncthreads();

    const int rA = wid * 16 + l15;

    // ---- proj pass: K=512 ----
    f32x4 acc_pj[2];
    acc_pj[0] = (f32x4){0.f, 0.f, 0.f, 0.f};
    acc_pj[1] = (f32x4){0.f, 0.f, 0.f, 0.f};
#pragma unroll
    for (int ks = 0; ks < 16; ++ks) {
        const int sp = (ks * 4 + l16) ^ l15;
        bf16x8 af = *reinterpret_cast<bf16x8*>(&As[rA * 512 + sp * 8]);
        const int kcol = ks * 32 + l16 * 8;
#pragma unroll
        for (int n2 = 0; n2 < 2; ++n2) {
            bf16x8 b2 = *reinterpret_cast<const bf16x8*>(
                &W2bf[(size_t)(n2 * 16 + l15) * 512 + kcol]);
            acc_pj[n2] = __builtin_amdgcn_mfma_f32_16x16x32_bf16(
                af, b2, acc_pj[n2], 0, 0, 0);
        }
    }

    // ---- 4 bn-stages: h-GEMM -> tanh -> Hs -> mulv ----
    f32x4 acc_mv[4];
#pragma unroll
    for (int n = 0; n < 4; ++n) acc_mv[n] = (f32x4){0.f, 0.f, 0.f, 0.f};

#pragma unroll 1
    for (int s = 0; s < 4; ++s) {
        const int bn = s * 128;
        f32x4 acc_h[8];
#pragma unroll
        for (int n = 0; n < 8; ++n) acc_h[n] = (f32x4){0.f, 0.f, 0.f, 0.f};
#pragma unroll
        for (int ks = 0; ks < 16; ++ks) {
            const int sp = (ks * 4 + l16) ^ l15;
            bf16x8 af = *reinterpret_cast<bf16x8*>(&As[rA * 512 + sp * 8]);
            const int kcol = ks * 32 + l16 * 8;
#pragma unroll
            for (int n = 0; n < 8; ++n) {
                bf16x8 bf = *reinterpret_cast<const bf16x8*>(
                    &W1T[(size_t)(bn + n * 16 + l15) * 512 + kcol]);
                acc_h[n] = __builtin_amdgcn_mfma_f32_16x16x32_bf16(
                    af, bf, acc_h[n], 0, 0, 0);
            }
        }
        __syncthreads();  // prior-stage mulv reads of Hs complete
#pragma unroll
        for (int n = 0; n < 8; ++n) {
            const float b1v = b1[bn + n * 16 + l15];
#pragma unroll
            for (int q = 0; q < 4; ++q) {
                const int row = wid * 16 + l16 * 4 + q;
                const int col = n * 16 + l15;
                const float hv = tanh_fast(acc_h[n][q] + b1v);
                const int sp2 = (col >> 3) ^ (row & 15);
                Hs[row * 128 + sp2 * 8 + (col & 7)] = f2bf(hv);
            }
        }
        __syncthreads();
#pragma unroll
        for (int ks2 = 0; ks2 < 4; ++ks2) {
            const int sp3 = (ks2 * 4 + l16) ^ l15;
            bf16x8 af2 = *reinterpret_cast<bf16x8*>(&Hs[rA * 128 + sp3 * 8]);
            const int kcol2 = bn + ks2 * 32 + l16 * 8;
#pragma unroll
            for (int n = 0; n < 4; ++n) {
                bf16x8 b2 = *reinterpret_cast<const bf16x8*>(
                    &Wt[(size_t)(n * 16 + l15) * 512 + kcol2]);
                acc_mv[n] = __builtin_amdgcn_mfma_f32_16x16x32_bf16(
                    af2, b2, acc_mv[n], 0, 0, 0);
            }
        }
    }

    // ---- epilogues ----
#pragma unroll
    for (int q = 0; q < 4; ++q) {
        const int row = bm + wid * 16 + l16 * 4 + q;
        proj[(size_t)row * 32 + l15] = acc_pj[0][q];
        proj[(size_t)row * 32 + 16 + l15] = acc_pj[1][q];
    }
    const int o0 = l15, o1 = 16 + l15;
    const float bm0 = bmu[o0], bm1 = bmu[o1];
    const float bl0 = blv[o0], bl1 = blv[o1];
#pragma unroll
    for (int q = 0; q < 4; ++q) {
        const int row = bm + wid * 16 + l16 * 4 + q;
        float mu0 = acc_mv[0][q] + bm0;
        float mu1 = acc_mv[1][q] + bm1;
        float lv0 = acc_mv[2][q] + bl0;
        float lv1 = acc_mv[3][q] + bl1;
        float e0 = eps[(size_t)row * 32 + o0];
        float e1 = eps[(size_t)row * 32 + o1];
        x[(size_t)row * 32 + o0] = mu0 + __expf(0.5f * lv0) * e0;
        x[(size_t)row * 32 + o1] = mu1 + __expf(0.5f * lv1) * e1;
        float pe = (e0 * e0 + lv0) + (e1 * e1 + lv1);
        pe += __shfl_xor(pe, 1, 64);
        pe += __shfl_xor(pe, 2, 64);
        pe += __shfl_xor(pe, 4, 64);
        pe += __shfl_xor(pe, 8, 64);
        if (l15 == 0) xent[row] = 0.5f * (pe + 32.f * LOG2PI);
    }
}

// ---------------------------------------------------------------------------
// K3: softmax_j(x[b,t-1] @ Wz + bz) -> ap1[t][s][e] = a[s][s^e]
// ---------------------------------------------------------------------------
__global__ __launch_bounds__(256) void k_loga(
    const float* __restrict__ x, const float* __restrict__ Wz,
    const float* __restrict__ bz, float* __restrict__ ap1)
{
    __shared__ float xs[32][32];
    const int tid = threadIdx.x;
    const int lane = tid & 63;
    const int wv = tid >> 6;
    const int itemBase = blockIdx.x * 32;
    {
        int r = tid >> 3, cc = (tid & 7) * 4;
        int item = itemBase + r;
        int src = (item & (NT - 1)) ? item - 1 : item;
        *reinterpret_cast<float4*>(&xs[r][cc]) =
            *reinterpret_cast<const float4*>(&x[(size_t)src * 32 + cc]);
    }
    float wcol[32];
#pragma unroll
    for (int e = 0; e < 32; ++e) wcol[e] = Wz[e * 64 + lane];
    const float bzv = bz[lane];
    __syncthreads();
    const int j = lane >> 3, k = lane & 7;
    for (int i = wv; i < 32; i += 4) {
        int item = itemBase + i;
        if ((item & (NT - 1)) == 0) continue;
        float acc = bzv;
#pragma unroll
        for (int e = 0; e < 32; ++e) acc = fmaf(xs[i][e], wcol[e], acc);
        float lse = lse8_high(acc);
        ap1[(size_t)item * 64 + j * 8 + (j ^ k)] = __expf(acc - lse);
    }
}

// ---------------------------------------------------------------------------
// K4: log_b (means in-register). Blocks 0..4091: 8 items each (t>=1);
// blocks 4092..4123: log_b[b][0] from x0 prior.
// ---------------------------------------------------------------------------
__global__ __launch_bounds__(256) void k_means8m(
    const float* __restrict__ x, const float* __restrict__ us,
    const float* __restrict__ A, const float* __restrict__ Bu,
    const float* __restrict__ bx, const float* __restrict__ x_logvar,
    const float* __restrict__ x0_mean, const float* __restrict__ x0_logvar,
    float* __restrict__ log_b)
{
    __shared__ float As[8192];
    __shared__ float xs8[8][32];
    __shared__ float us8[8][2];
    const int tid = threadIdx.x;
    if (blockIdx.x >= 4092) {
        const int b = blockIdx.x - 4092;
        const int k = tid >> 5, xo = tid & 31;
        float xv = x[((size_t)b * NT) * 32 + xo];
        float mm = x0_mean[k * 32 + xo];
        float lvv = x0_logvar[k * 32 + xo];
        float dd = xv - mm;
        float term = -0.5f * (dd * dd * __expf(-lvv) + lvv + LOG2PI);
        for (int m = 16; m; m >>= 1) term += __shfl_down(term, m, 32);
        if (xo == 0) log_b[(size_t)b * NT * 8 + k] = term;
        return;
    }
    const int base = blockIdx.x * 8;
    for (int i = tid; i < 2048; i += 256)
        reinterpret_cast<float4*>(As)[i] =
            reinterpret_cast<const float4*>(A)[i];
    {
        int row = tid >> 5, xo = tid & 31;
        int item = base + row;
        int b = item / 1023, tm = item - b * 1023;
        xs8[row][xo] = x[((size_t)b * NT + tm) * 32 + xo];
        if (xo < 2) us8[row][xo] = us[((size_t)b * NT + tm + 1) * 2 + xo];
    }
    __syncthreads();
    const int k = tid >> 5, xo = tid & 31;
    const float bxv = bx[k * 32 + xo];
    const float bu0 = Bu[(k * 2 + 0) * 32 + xo];
    const float bu1 = Bu[(k * 2 + 1) * 32 + xo];
    const float lvv = x_logvar[k * 32 + xo];
    const float ivv = __expf(-lvv);
    const float basev = lvv + LOG2PI;
    for (int i = 0; i < 8; ++i) {
        int item = base + i;
        int b = item / 1023, tm = item - b * 1023;
        float acc = fmaf(us8[i][0], bu0, fmaf(us8[i][1], bu1, bxv));
#pragma unroll 8
        for (int e = 0; e < 32; ++e)
            acc = fmaf(xs8[i][e], As[k * 1024 + e * 32 + xo], acc);
        float xv = x[((size_t)b * NT + tm + 1) * 32 + xo];
        float dd = xv - acc;
        float term = dd * dd * ivv + basev;
        for (int m = 16; m; m >>= 1) term += __shfl_down(term, m, 32);
        if (xo == 0)
            log_b[((size_t)b * NT + tm + 1) * 8 + k] = -0.5f * term;
    }
}

// ---------------------------------------------------------------------------
// K4c: bexp/mbsum prep
// ---------------------------------------------------------------------------
__global__ __launch_bounds__(256) void k_prep(
    const float* __restrict__ log_b, float* __restrict__ bexp,
    float* __restrict__ mbsum)
{
    __shared__ float part[256];
    const int b = blockIdx.x;
    const int tid = threadIdx.x;
    float msum = 0.f;
    for (int t = tid; t < NT; t += 256) {
        const float* lbp = &log_b[((size_t)b * NT + t) * 8];
        float4 l0 = *reinterpret_cast<const float4*>(lbp);
        float4 l1 = *reinterpret_cast<const float4*>(lbp + 4);
        float mm = fmaxf(fmaxf(fmaxf(l0.x, l0.y), fmaxf(l0.z, l0.w)),
                         fmaxf(fmaxf(l1.x, l1.y), fmaxf(l1.z, l1.w)));
        float4 e0, e1;
        e0.x = __expf(l0.x - mm); e0.y = __expf(l0.y - mm);
        e0.z = __expf(l0.z - mm); e0.w = __expf(l0.w - mm);
        e1.x = __expf(l1.x - mm); e1.y = __expf(l1.y - mm);
        e1.z = __expf(l1.z - mm); e1.w = __expf(l1.w - mm);
        float* bp = &bexp[((size_t)b * NT + t) * 8];
        *reinterpret_cast<float4*>(bp) = e0;
        *reinterpret_cast<float4*>(bp + 4) = e1;
        msum += mm;
    }
    part[tid] = msum;
    __syncthreads();
    for (int s = 128; s; s >>= 1) {
        if (tid < s) part[tid] += part[tid + s];
        __syncthreads();
    }
    if (tid == 0) mbsum[b] = part[0];
}

// ---------------------------------------------------------------------------
// K5a: chunk products (wave per (b,chunk)).
// ---------------------------------------------------------------------------
__global__ __launch_bounds__(256) void k_fbA(
    const float* __restrict__ ap1, const float* __restrict__ bexp,
    float* __restrict__ Pfx, float* __restrict__ sA)
{
    const int tid = threadIdx.x;
    const int wg = blockIdx.x * 4 + (tid >> 6);
    const int lane = tid & 63;
    const int b = wg / NCH;
    const int c = wg - b * NCH;
    const int j = lane >> 3, k = lane & 7;
    const float* ap = &ap1[(size_t)b * NT * 64];
    const float* be = &bexp[(size_t)b * NT * 8];
    int t = CHL * c + 1;
    float P = be[t * 8 + j] * ap[t * 64 + j * 8 + (j ^ k)];
    float sacc = 0.f;
    for (int i = 1; i < CHL; ++i) {
        ++t;
        float4 m0 = *reinterpret_cast<const float4*>(&ap[(size_t)t * 64 + j * 8]);
        float4 m1 = *reinterpret_cast<const float4*>(&ap[(size_t)t * 64 + j * 8 + 4]);
        float bj = be[(size_t)t * 8 + j];
        float x1 = __shfl_xor(P, 8, 64);
        float x2 = __shfl_xor(P, 16, 64);
        float x3 = __shfl_xor(P, 24, 64);
        float x4 = __shfl_xor(P, 32, 64);
        float x5 = __shfl_xor(P, 40, 64);
        float x6 = __shfl_xor(P, 48, 64);
        float x7 = __shfl_xor(P, 56, 64);
        float c0 = fmaf(m0.y, x1, m0.x * P);
        float c1 = fmaf(m0.w, x3, m0.z * x2);
        float c2 = fmaf(m1.y, x5, m1.x * x4);
        float c3 = fmaf(m1.w, x7, m1.z * x6);
        P = bj * ((c0 + c1) + (c2 + c3));
        if ((i & 3) == 3) {
            float mx = P;
            mx = fmaxf(mx, __shfl_xor(mx, 1, 64));
            mx = fmaxf(mx, __shfl_xor(mx, 2, 64));
            mx = fmaxf(mx, __shfl_xor(mx, 4, 64));
            mx = fmaxf(mx, __shfl_xor(mx, 8, 64));
            mx = fmaxf(mx, __shfl_xor(mx, 16, 64));
            mx = fmaxf(mx, __shfl_xor(mx, 32, 64));
            mx = fmaxf(mx, 1e-30f);
            float r = __builtin_amdgcn_rcpf(mx);
            P *= r;
            sacc -= __logf(r);
        }
    }
    Pfx[((size_t)b * NCH + c) * 64 + j * 8 + (j ^ k)] = P;
    if (lane == 0) sA[b * NCH + c] = sacc;
}

// ---------------------------------------------------------------------------
// K5b: boundary scans over chunk matrices.
// ---------------------------------------------------------------------------
__global__ __launch_bounds__(128) void k_fbB(
    const float* __restrict__ Pfx, const float* __restrict__ sA,
    const float* __restrict__ bexp, const float* __restrict__ mbsum,
    const float* __restrict__ log_init_z,
    float* __restrict__ alphaB, float* __restrict__ betaB,
    float* __restrict__ log_px)
{
    const int b = blockIdx.x;
    const int tid = threadIdx.x;
    const int wave = tid >> 6;
    const int lane = tid & 63;
    const int st = lane & 7;
    const float* pf = &Pfx[(size_t)b * NCH * 64];
    if (wave == 0) {
        float liv[8];
        float mz = -1e30f, sz = 0.f;
#pragma unroll
        for (int q = 0; q < 8; ++q) liv[q] = log_init_z[q];
#pragma unroll
        for (int q = 0; q < 8; ++q) mz = fmaxf(mz, liv[q]);
#pragma unroll
        for (int q = 0; q < 8; ++q) sz += __expf(liv[q] - mz);
        float alpha = (__expf(liv[st] - mz) / sz) * bexp[(size_t)b * NT * 8 + st];
        float logS = 0.f, sAsum = 0.f;
        {
            float s = fmaxf(gsum8(alpha), 1e-35f);
            logS += __logf(s);
            alpha *= __builtin_amdgcn_rcpf(s);
        }
        if (lane < 8) alphaB[((size_t)b * (NCH + 1)) * 8 + lane] = alpha;
        for (int c = 0; c < NCH; ++c) {
            float4 a0 = *reinterpret_cast<const float4*>(&pf[(size_t)c * 64 + st * 8]);
            float4 a1 = *reinterpret_cast<const float4*>(&pf[(size_t)c * 64 + st * 8 + 4]);
            alpha = fb_matvec(a0, a1, alpha);
            float s = fmaxf(gsum8(alpha), 1e-35f);
            logS += __logf(s);
            alpha *= __builtin_amdgcn_rcpf(s);
            sAsum += sA[b * NCH + c];
            if (lane < 8) alphaB[((size_t)b * (NCH + 1) + c + 1) * 8 + lane] = alpha;
        }
        if (lane == 0) log_px[b] = mbsum[b] + sAsum + logS;
    } else {
        float beta = 1.f;
        if (lane < 8) betaB[((size_t)b * (NCH + 1) + NCH) * 8 + lane] = 1.f;
        for (int c = NCH - 1; c >= 0; --c) {
            float4 a0 = *reinterpret_cast<const float4*>(&pf[(size_t)c * 64 + st * 8]);
            float4 a1 = *reinterpret_cast<const float4*>(&pf[(size_t)c * 64 + st * 8 + 4]);
            beta = fb_matvecT(a0, a1, beta);
            float s = fmaxf(gsum8(beta), 1e-35f);
            beta *= __builtin_amdgcn_rcpf(s);
            if (lane < 8) betaB[((size_t)b * (NCH + 1) + c) * 8 + lane] = beta;
        }
    }
}

// ---------------------------------------------------------------------------
// K5c: within-chunk recompute + gamma.
// ---------------------------------------------------------------------------
__global__ __launch_bounds__(256) void k_fbC(
    const float* __restrict__ ap1, const float* __restrict__ bexp,
    const float* __restrict__ alphaB, const float* __restrict__ betaB,
    float* __restrict__ gamma)
{
    __shared__ float alphaS[32][CHL][8];
    const int tid = threadIdx.x;
    const int g = tid >> 3;
    const int st = tid & 7;
    const int task = blockIdx.x * 32 + g;
    const int b = task / NCH;
    const int c = task - b * NCH;
    const float* ap = &ap1[(size_t)b * NT * 64];
    const float* be = &bexp[(size_t)b * NT * 8];
    const int t0 = CHL * c;
    float alpha = alphaB[((size_t)b * (NCH + 1) + c) * 8 + st];
#pragma unroll
    for (int i = 1; i <= CHL; ++i) {
        int t = t0 + i;
        float4 a0 = *reinterpret_cast<const float4*>(&ap[(size_t)t * 64 + st * 8]);
        float4 a1 = *reinterpret_cast<const float4*>(&ap[(size_t)t * 64 + st * 8 + 4]);
        float bv = be[(size_t)t * 8 + st];
        alpha = fb_matvec(a0, a1, alpha) * bv;
        if (i == 5)
            alpha *= __builtin_amdgcn_rcpf(fmaxf(gsum8(alpha), 1e-35f));
        alphaS[g][i - 1][st] = alpha;
    }
    float beta = betaB[((size_t)b * (NCH + 1) + c + 1) * 8 + st];
#pragma unroll
    for (int i = CHL; i >= 1; --i) {
        int t = t0 + i;
        float gv = alphaS[g][i - 1][st] * beta;
        float s = fmaxf(gsum8(gv), 1e-35f);
        gamma[((size_t)b * NT + t) * 8 + st] = gv * __builtin_amdgcn_rcpf(s);
        float4 a0 = *reinterpret_cast<const float4*>(&ap[(size_t)t * 64 + st * 8]);
        float4 a1 = *reinterpret_cast<const float4*>(&ap[(size_t)t * 64 + st * 8 + 4]);
        float bv = be[(size_t)t * 8 + st];
        beta = fb_matvecT(a0, a1, beta * bv);
        if (i == 6)
            beta *= __builtin_amdgcn_rcpf(fmaxf(gsum8(beta), 1e-35f));
    }
    if (c == 0) {
        float a0v = alphaB[((size_t)b * (NCH + 1)) * 8 + st];
        float gv = a0v * beta;
        float s = fmaxf(gsum8(gv), 1e-35f);
        gamma[((size_t)b * NT) * 8 + st] = gv * __builtin_amdgcn_rcpf(s);
    }
}

// ---------------------------------------------------------------------------
// K6: emission via recomputed gamma-mixed mean + factorized quadratic form.
// ---------------------------------------------------------------------------
__global__ __launch_bounds__(256) void k_py(
    const float* __restrict__ x, const float* __restrict__ us,
    const float* __restrict__ A, const float* __restrict__ Bu,
    const float* __restrict__ bx, const float* __restrict__ gamma,
    const float* __restrict__ proj, const float* __restrict__ term1,
    const float* __restrict__ Gm, const float* __restrict__ c2x,
    const float* __restrict__ xent, float* __restrict__ red)
{
    __shared__ float As[8192];
    __shared__ float Gs[32 * 33];
    __shared__ float c2s[32];
    __shared__ float xp8[8][32];
    __shared__ float gs[8][8];
    __shared__ float us8[8][2];
    __shared__ float xgS[8][32];
    const int tid = threadIdx.x;
    const int itemBase = blockIdx.x * 8;
    const int t0 = itemBase & (NT - 1);
    for (int i = tid; i < 2048; i += 256)
        reinterpret_cast<float4*>(As)[i] =
            reinterpret_cast<const float4*>(A)[i];
    for (int i = tid; i < 32 * 33; i += 256) Gs[i] = Gm[i];
    if (tid < 32) c2s[tid] = c2x[tid];
    {
        int it = tid >> 5, xo = tid & 31;
        int t = t0 + it;
        int item = itemBase + it;
        xp8[it][xo] = (t > 0) ? x[((size_t)item - 1) * 32 + xo] : 0.f;
        if (xo < 8) gs[it][xo] = (t > 0) ? gamma[(size_t)item * 8 + xo] : 0.f;
        if (xo < 2) us8[it][xo] = (t > 0) ? us[(size_t)item * 2 + xo] : 0.f;
    }
    __syncthreads();
    const int it = tid >> 5;
    const int xo = tid & 31;
    const int t = t0 + it;
    const int item = itemBase + it;
    float xg;
    if (t == 0) {
        xg = x[(size_t)item * 32 + xo];
    } else {
        xg = 0.f;
#pragma unroll
        for (int k = 0; k < 8; ++k) {
            float acc = bx[k * 32 + xo];
            acc = fmaf(us8[it][0], Bu[(k * 2 + 0) * 32 + xo], acc);
            acc = fmaf(us8[it][1], Bu[(k * 2 + 1) * 32 + xo], acc);
#pragma unroll 8
            for (int e = 0; e < 32; ++e)
                acc = fmaf(xp8[it][e], As[k * 1024 + e * 32 + xo], acc);
            xg = fmaf(gs[it][k], acc, xg);
        }
    }
    xgS[it][xo] = xg;
    __syncthreads();
    float gmv = 0.f;
#pragma unroll 8
    for (int y = 0; y < 32; ++y)
        gmv = fmaf(Gs[xo * 33 + y], xgS[it][y], gmv);
    float val = xg * (proj[(size_t)item * 32 + xo] - c2s[xo] - 0.5f * gmv);
    val += __shfl_xor(val, 1, 64);
    val += __shfl_xor(val, 2, 64);
    val += __shfl_xor(val, 4, 64);
    val += __shfl_xor(val, 8, 64);
    val += __shfl_xor(val, 16, 64);
    if (xo == 0)
        red[item] = -0.5f * term1[item] + val + xent[item];
}

// ---------------------------------------------------------------------------
// K7: elbo = (sum red + sum log_px)/NB - 512*sum(ylv+LOG2PI)
// ---------------------------------------------------------------------------
__global__ __launch_bounds__(256) void k_final(
    const float* __restrict__ red, const float* __restrict__ log_px,
    const float* __restrict__ ylv, float* __restrict__ out)
{
    __shared__ float ssum[4];
    __shared__ float ssum2[4];
    const int tid = threadIdx.x;
    float s = 0.f, t = 0.f;
    for (int i = tid; i < NB * NT; i += 256) s += red[i];
    if (tid < NB) s += log_px[tid];
    for (int i = tid; i < 512; i += 256) t += ylv[i] + LOG2PI;
#pragma unroll
    for (int m = 1; m < 64; m <<= 1) {
        s += __shfl_xor(s, m, 64);
        t += __shfl_xor(t, m, 64);
    }
    if ((tid & 63) == 0) { ssum[tid >> 6] = s; ssum2[tid >> 6] = t; }
    __syncthreads();
    if (tid == 0) {
        float S = ssum[0] + ssum[1] + ssum[2] + ssum[3];
        float T = ssum2[0] + ssum2[1] + ssum2[2] + ssum2[3];
        out[0] = S / (float)NB - 512.0f * T;
    }
}

// ---------------------------------------------------------------------------
extern "C" void kernel_launch(void* const* d_in, const int* in_sizes, int n_in,
                              void* d_out, int out_size, void* d_ws,
                              size_t ws_size, hipStream_t stream)
{
    const float* ys        = (const float*)d_in[0];
    const float* us        = (const float*)d_in[1];
    const float* eps       = (const float*)d_in[2];
    const float* W1        = (const float*)d_in[3];
    const float* b1        = (const float*)d_in[4];
    const float* Wmu       = (const float*)d_in[5];
    const float* bmu       = (const float*)d_in[6];
    const float* Wlv       = (const float*)d_in[7];
    const float* blv       = (const float*)d_in[8];
    const float* Wz        = (const float*)d_in[9];
    const float* bz        = (const float*)d_in[10];
    const float* A         = (const float*)d_in[11];
    const float* Bu        = (const float*)d_in[12];
    const float* bx        = (const float*)d_in[13];
    const float* x_logvar  = (const float*)d_in[14];
    const float* x0_mean   = (const float*)d_in[15];
    const float* x0_logvar = (const float*)d_in[16];
    const float* C         = (const float*)d_in[17];
    const float* dv        = (const float*)d_in[18];
    const float* y_logvar  = (const float*)d_in[19];
    const float* log_init_z= (const float*)d_in[20];
    float* out = (float*)d_out;

    float* ws = (float*)d_ws;
    float* x      = ws;                    //  1,048,576
    float* xent   = x + 1048576;           //     32,768
    float* ap1    = xent + 32768;          //  2,097,152
    float* bexp   = ap1 + 2097152;         //    262,144
    float* log_b  = bexp + 262144;         //    262,144
    float* gam    = log_b + 262144;        //    262,144
    float* log_px = gam + 262144;          //         32
    float* mbsum  = log_px + 32;           //         32
    float* red    = mbsum + 32;            //     32,768
    float* w1t_f  = red + 32768;           //    131,072 (W1^T bf16)
    float* wmlv_f = w1t_f + 131072;        //     16,384 (Wmu|Wlv^T bf16)
    float* proj   = wmlv_f + 16384;        //  1,048,576
    float* term1  = proj + 1048576;        //     32,768
    float* w2bf_f = term1 + 32768;         //      8,192 (W2 bf16)
    float* Gm     = w2bf_f + 8192;         //      1,056
    float* c2x    = Gm + 1056;             //         32
    float* Pfx    = c2x + 32;              //    190,464
    float* sA     = Pfx + 190464;          //      2,976
    float* alphaB = sA + 2976;             //     24,064
    float* betaB  = alphaB + 24064;        //     24,064

    unsigned short* w1t  = (unsigned short*)w1t_f;
    unsigned short* wmlv = (unsigned short*)wmlv_f;
    unsigned short* w2bf = (unsigned short*)w2bf_f;

    k_prep_w  <<<321, 256, 0, stream>>>(W1, Wmu, Wlv, C, dv, y_logvar,
                                        w1t, wmlv, w2bf, Gm, c2x);
    k_mlp2    <<<512, 256, 0, stream>>>(ys, w1t, wmlv, w2bf, b1, bmu, blv,
                                        eps, dv, y_logvar, x, xent, proj, term1);
    k_loga    <<<1024, 256, 0, stream>>>(x, Wz, bz, ap1);
    k_means8m <<<4124, 256, 0, stream>>>(x, us, A, Bu, bx, x_logvar,
                                         x0_mean, x0_logvar, log_b);
    k_prep    <<<32, 256, 0, stream>>>(log_b, bexp, mbsum);
    k_fbA     <<<744, 256, 0, stream>>>(ap1, bexp, Pfx, sA);
    k_fbB     <<<32, 128, 0, stream>>>(Pfx, sA, bexp, mbsum, log_init_z,
                                       alphaB, betaB, log_px);
    k_fbC     <<<93, 256, 0, stream>>>(ap1, bexp, alphaB, betaB, gam);
    k_py      <<<4096, 256, 0, stream>>>(x, us, A, Bu, bx, gam, proj, term1,
                                         Gm, c2x, xent, red);
    k_final   <<<1, 256, 0, stream>>>(red, log_px, y_logvar, out);
}

// Round 10
// 356.916 us; speedup vs baseline: 1.2993x; 1.2993x over previous
//
#include <hip/hip_runtime.h>
#include <math.h>

#define LOG2PI 1.8378770664093453f

// Problem sizes (fixed)
#define NB 32
#define NT 1024
#define ND 512
#define NH 512
#define NX 32
#define NK 8
#define NU 2

// chunked scan: 1023 transitions = 93 chunks x 11
#define NCH 93
#define CHL 11

typedef __attribute__((ext_vector_type(8))) short bf16x8;
typedef __attribute__((ext_vector_type(4))) float f32x4;

__device__ __forceinline__ unsigned short f2bf(float f) {
    unsigned u = __float_as_uint(f);
    unsigned r = (u + 0x7FFF + ((u >> 16) & 1)) >> 16;
    return (unsigned short)r;
}

// pack two f32 -> two bf16 (round-half-up): 2 adds + 1 v_perm
__device__ __forceinline__ unsigned pack_bf2(float a, float b) {
    unsigned ua = __float_as_uint(a) + 0x8000u;
    unsigned ub = __float_as_uint(b) + 0x8000u;
    return __builtin_amdgcn_perm(ub, ua, 0x07060302);
}

// fast tanh: 1 - 2/(e^{2x}+1)
__device__ __forceinline__ float tanh_fast(float v) {
    float t = __expf(2.0f * v);
    return 1.0f - 2.0f * __builtin_amdgcn_rcpf(t + 1.0f);
}

// ---------------------------------------------------------------------------
// DPP xor-shuffles within 8-lane groups
// ---------------------------------------------------------------------------
#define DPP_X1 0xB1
#define DPP_X2 0x4E
#define DPP_X3 0x1B
#define DPP_X7 0x141

template <int CTRL>
__device__ __forceinline__ float dppx(float v) {
    return __int_as_float(__builtin_amdgcn_update_dpp(
        0, __float_as_int(v), CTRL, 0xF, 0xF, true));
}

__device__ __forceinline__ float fb_matvec(float4 a0, float4 a1, float v) {
    float p1 = dppx<DPP_X1>(v);
    float p2 = dppx<DPP_X2>(v);
    float p3 = dppx<DPP_X3>(v);
    float p7 = dppx<DPP_X7>(v);
    float p4 = dppx<DPP_X7>(p3);
    float p5 = dppx<DPP_X7>(p2);
    float p6 = dppx<DPP_X7>(p1);
    float c0 = fmaf(a0.y, p1, a0.x * v);
    float c1 = fmaf(a0.w, p3, a0.z * p2);
    float c2 = fmaf(a1.y, p5, a1.x * p4);
    float c3 = fmaf(a1.w, p7, a1.z * p6);
    return (c0 + c1) + (c2 + c3);
}

__device__ __forceinline__ float fb_matvecT(float4 a0, float4 a1, float w) {
    float q0 = a0.x * w;
    float t1 = dppx<DPP_X1>(a0.y * w);
    float t2 = dppx<DPP_X2>(a0.z * w);
    float t3 = dppx<DPP_X3>(a0.w * w);
    float t7 = dppx<DPP_X7>(a1.w * w);
    float t4 = dppx<DPP_X7>(dppx<DPP_X3>(a1.x * w));
    float t5 = dppx<DPP_X7>(dppx<DPP_X2>(a1.y * w));
    float t6 = dppx<DPP_X7>(dppx<DPP_X1>(a1.z * w));
    return ((q0 + t1) + (t2 + t3)) + ((t4 + t5) + (t6 + t7));
}

__device__ __forceinline__ float gsum8(float v) {
    float s = v + dppx<DPP_X1>(v);
    s = s + dppx<DPP_X2>(s);
    s = s + dppx<DPP_X7>(dppx<DPP_X3>(s));
    return s;
}

// max over 8 consecutive floats held as two float4
__device__ __forceinline__ float max8(float4 l0, float4 l1) {
    return fmaxf(fmaxf(fmaxf(l0.x, l0.y), fmaxf(l0.z, l0.w)),
                 fmaxf(fmaxf(l1.x, l1.y), fmaxf(l1.z, l1.w)));
}

__device__ __forceinline__ float lse8_high(float v) {
    float m = v;
    m = fmaxf(m, __shfl_xor(m, 8, 64));
    m = fmaxf(m, __shfl_xor(m, 16, 64));
    m = fmaxf(m, __shfl_xor(m, 32, 64));
    float s = __expf(v - m);
    s += __shfl_xor(s, 8, 64);
    s += __shfl_xor(s, 16, 64);
    s += __shfl_xor(s, 32, 64);
    return m + __logf(s);
}

// ---------------------------------------------------------------------------
// K_prep_w: merged weight prep.
//   blocks 0-255   : W1 -> W1T bf16
//   blocks 256-287 : Wmu/Wlv -> wmlv [64][512] bf16
//   blocks 288-319 : G[x][y] + c2x[x]
//   block  320     : W2bf = bf16(exp(-ylv)*C), ivbuf = exp(-ylv)
// ---------------------------------------------------------------------------
__global__ __launch_bounds__(256) void k_prep_w(
    const float* __restrict__ W1, const float* __restrict__ Wmu,
    const float* __restrict__ Wlv, const float* __restrict__ C,
    const float* __restrict__ dvec, const float* __restrict__ ylv,
    unsigned short* __restrict__ WT, unsigned short* __restrict__ wmlv,
    unsigned short* __restrict__ W2bf, float* __restrict__ G,
    float* __restrict__ c2x, float* __restrict__ ivbuf)
{
    __shared__ float tile[32][33];
    const int bid = blockIdx.x;
    const int tid = threadIdx.x;
    if (bid < 256) {
        const int bx = (bid & 15) * 32;
        const int by = (bid >> 4) * 32;
        const int tx = tid & 31, ty = tid >> 5;
        for (int i = ty; i < 32; i += 8)
            tile[i][tx] = W1[(size_t)(bx + i) * 512 + by + tx];
        __syncthreads();
        for (int i = ty; i < 32; i += 8)
            WT[(size_t)(by + i) * 512 + bx + tx] = f2bf(tile[tx][i]);
        return;
    }
    if (bid < 288) {
        const int t = bid - 256;
        const float* W = (t >> 4) ? Wlv : Wmu;
        const int base = (t >> 4) * 32;
        const int g = t & 15;
        const int tx = tid & 31, ty = tid >> 5;
        for (int i = ty; i < 32; i += 8)
            tile[i][tx] = W[(size_t)(g * 32 + i) * 32 + tx];
        __syncthreads();
        for (int i = ty; i < 32; i += 8)
            wmlv[(size_t)(base + i) * 512 + g * 32 + tx] = f2bf(tile[tx][i]);
        return;
    }
    if (bid == 320) {
        for (int i = tid; i < 32 * 512; i += 256)
            W2bf[i] = f2bf(C[i] * __expf(-ylv[i & 511]));
        ivbuf[tid] = __expf(-ylv[tid]);
        ivbuf[tid + 256] = __expf(-ylv[tid + 256]);
        return;
    }
    const int x = bid - 288;
    const int y = tid >> 3, seg = tid & 7;
    const float* Cx = &C[(size_t)x * 512];
    const float* Cy = &C[(size_t)y * 512];
    float p = 0.f;
    for (int j = 0; j < 64; ++j) {
        int dcol = seg * 64 + j;
        p = fmaf(Cx[dcol] * __expf(-ylv[dcol]), Cy[dcol], p);
    }
    p = gsum8(p);
    if (seg == 0) G[x * 33 + y] = p;
    if (tid < 8) {
        float q = 0.f;
        for (int j = 0; j < 64; ++j) {
            int dcol = tid * 64 + j;
            q = fmaf(Cx[dcol] * __expf(-ylv[dcol]), dvec[dcol], q);
        }
        q = gsum8(q);
        if (tid == 0) c2x[x] = q;
    }
}

// ---------------------------------------------------------------------------
// K1: h = bf16(tanh(ys@W1+b1)), 128x128 tile, f32 ys staged with inline cast.
// XCD swizzle: 4 bn-blocks of each bm-slab land on the SAME XCD.
// Riders (bn==0 blocks only): term1 (staging loop) + proj (reuses A-frags).
// ---------------------------------------------------------------------------
__global__ __launch_bounds__(256) void k_gemm_h_mfma(
    const float* __restrict__ ys,
    const unsigned short* __restrict__ W1T,
    const unsigned short* __restrict__ W2bf,
    const float* __restrict__ b1,
    const float* __restrict__ dvec, const float* __restrict__ ivbuf,
    unsigned short* __restrict__ hb,
    float* __restrict__ proj, float* __restrict__ term1)
{
    __shared__ unsigned short As[128 * 64];
    __shared__ unsigned short Bs[128 * 64];
    const int tid = threadIdx.x;
    const int L = blockIdx.x;
    const int xcd = L & 7, rr = L >> 3;
    const int bm = (xcd * 32 + (rr >> 2)) * 128;
    const int bn = (rr & 3) * 128;
    const bool rider = (bn == 0);
    const int wid = tid >> 6, lane = tid & 63;
    const int wm = wid >> 1, wn = wid & 1;
    const int l15 = lane & 15, l16 = lane >> 4;
    const int c8 = tid & 7;

    f32x4 acc[4][4];
#pragma unroll
    for (int m = 0; m < 4; ++m)
#pragma unroll
        for (int n = 0; n < 4; ++n)
            acc[m][n] = (f32x4){0.f, 0.f, 0.f, 0.f};
    f32x4 acc_pj[2][2];
    acc_pj[0][0] = acc_pj[0][1] = acc_pj[1][0] = acc_pj[1][1] =
        (f32x4){0.f, 0.f, 0.f, 0.f};
    float t1p[4] = {0.f, 0.f, 0.f, 0.f};

    for (int k0 = 0; k0 < 512; k0 += 64) {
        float4 dv0, dv1, iv0, iv1;
        if (rider) {
            dv0 = *reinterpret_cast<const float4*>(&dvec[k0 + c8 * 8]);
            dv1 = *reinterpret_cast<const float4*>(&dvec[k0 + c8 * 8 + 4]);
            iv0 = *reinterpret_cast<const float4*>(&ivbuf[k0 + c8 * 8]);
            iv1 = *reinterpret_cast<const float4*>(&ivbuf[k0 + c8 * 8 + 4]);
        }
#pragma unroll
        for (int r4 = 0; r4 < 4; ++r4) {
            int l = tid + r4 * 256;
            int row = l >> 3;
            int sidx = row * 8 + (c8 ^ (row & 7));
            const float4 f0 = *reinterpret_cast<const float4*>(
                &ys[(size_t)(bm + row) * 512 + k0 + c8 * 8]);
            const float4 f1 = *reinterpret_cast<const float4*>(
                &ys[(size_t)(bm + row) * 512 + k0 + c8 * 8 + 4]);
            if (rider) {
                float g0 = f0.x - dv0.x, g1 = f0.y - dv0.y;
                float g2 = f0.z - dv0.z, g3 = f0.w - dv0.w;
                float g4 = f1.x - dv1.x, g5 = f1.y - dv1.y;
                float g6 = f1.z - dv1.z, g7 = f1.w - dv1.w;
                t1p[r4] += (g0 * g0 * iv0.x + g1 * g1 * iv0.y)
                         + (g2 * g2 * iv0.z + g3 * g3 * iv0.w)
                         + (g4 * g4 * iv1.x + g5 * g5 * iv1.y)
                         + (g6 * g6 * iv1.z + g7 * g7 * iv1.w);
            }
            uint4 ua;
            ua.x = pack_bf2(f0.x, f0.y);
            ua.y = pack_bf2(f0.z, f0.w);
            ua.z = pack_bf2(f1.x, f1.y);
            ua.w = pack_bf2(f1.z, f1.w);
            *reinterpret_cast<uint4*>(&As[sidx * 8]) = ua;
            uint4 vb = *reinterpret_cast<const uint4*>(
                &W1T[(size_t)(bn + row) * 512 + k0 + c8 * 8]);
            *reinterpret_cast<uint4*>(&Bs[sidx * 8]) = vb;
        }
        __syncthreads();
#pragma unroll
        for (int kh = 0; kh < 2; ++kh) {
            bf16x8 af[4], bfr[4];
            const int c8r = kh * 4 + l16;
#pragma unroll
            for (int m = 0; m < 4; ++m) {
                int rA = wm * 64 + m * 16 + l15;
                af[m] = *reinterpret_cast<bf16x8*>(
                    &As[rA * 64 + (c8r ^ (rA & 7)) * 8]);
            }
#pragma unroll
            for (int n = 0; n < 4; ++n) {
                int rB = wn * 64 + n * 16 + l15;
                bfr[n] = *reinterpret_cast<bf16x8*>(
                    &Bs[rB * 64 + (c8r ^ (rB & 7)) * 8]);
            }
#pragma unroll
            for (int m = 0; m < 4; ++m)
#pragma unroll
                for (int n = 0; n < 4; ++n)
                    acc[m][n] = __builtin_amdgcn_mfma_f32_16x16x32_bf16(
                        af[m], bfr[n], acc[m][n], 0, 0, 0);
            if (rider) {
                const int mm0 = wn ? 2 : 0;
#pragma unroll
                for (int mi = 0; mi < 2; ++mi)
#pragma unroll
                    for (int n2 = 0; n2 < 2; ++n2) {
                        bf16x8 b2 = *reinterpret_cast<const bf16x8*>(
                            &W2bf[(size_t)(n2 * 16 + l15) * 512 + k0 + c8r * 8]);
                        acc_pj[mi][n2] = __builtin_amdgcn_mfma_f32_16x16x32_bf16(
                            af[mm0 + mi], b2, acc_pj[mi][n2], 0, 0, 0);
                    }
            }
        }
        __syncthreads();
    }
    // h epilogue
    float b1v[4];
#pragma unroll
    for (int n = 0; n < 4; ++n)
        b1v[n] = b1[bn + wn * 64 + n * 16 + l15];
#pragma unroll
    for (int m = 0; m < 4; ++m) {
#pragma unroll
        for (int q = 0; q < 4; ++q) {
            int row = bm + wm * 64 + m * 16 + l16 * 4 + q;
#pragma unroll
            for (int n = 0; n < 4; ++n) {
                int col = bn + wn * 64 + n * 16 + l15;
                hb[(size_t)row * 512 + col] =
                    f2bf(tanh_fast(acc[m][n][q] + b1v[n]));
            }
        }
    }
    if (rider) {
        const int mm0 = wn ? 2 : 0;
#pragma unroll
        for (int mi = 0; mi < 2; ++mi)
#pragma unroll
            for (int q = 0; q < 4; ++q) {
                int row = bm + wm * 64 + (mm0 + mi) * 16 + l16 * 4 + q;
                proj[(size_t)row * 32 + l15] = acc_pj[mi][0][q];
                proj[(size_t)row * 32 + 16 + l15] = acc_pj[mi][1][q];
            }
#pragma unroll
        for (int r4 = 0; r4 < 4; ++r4) {
            float s = t1p[r4];
            s += __shfl_xor(s, 1, 64);
            s += __shfl_xor(s, 2, 64);
            s += __shfl_xor(s, 4, 64);
            if ((tid & 7) == 0) term1[bm + r4 * 32 + (tid >> 3)] = s;
        }
    }
}

// ---------------------------------------------------------------------------
// K2: [mu|lv] = h_bf @ Wt^T via MFMA; epilogue fuses x, xent
// ---------------------------------------------------------------------------
__global__ __launch_bounds__(256) void k_mulv_mfma(
    const unsigned short* __restrict__ hbf,
    const unsigned short* __restrict__ Wt,
    const float* __restrict__ bmu, const float* __restrict__ blv,
    const float* __restrict__ eps,
    float* __restrict__ x, float* __restrict__ xent)
{
    __shared__ unsigned short As[128 * 64];
    __shared__ unsigned short Bs[64 * 64];
    const int tid = threadIdx.x;
    const int bm = blockIdx.x * 128;
    const int wid = tid >> 6, lane = tid & 63;
    f32x4 acc[2][4];
#pragma unroll
    for (int m = 0; m < 2; ++m)
#pragma unroll
        for (int n = 0; n < 4; ++n)
            acc[m][n] = (f32x4){0.f, 0.f, 0.f, 0.f};

    for (int k0 = 0; k0 < 512; k0 += 64) {
#pragma unroll
        for (int r = 0; r < 4; ++r) {
            int l = tid + r * 256, row = l >> 3, c8 = l & 7;
            int sidx = row * 8 + (c8 ^ (row & 7));
            uint4 v = *reinterpret_cast<const uint4*>(
                &hbf[(size_t)(bm + row) * 512 + k0 + c8 * 8]);
            *reinterpret_cast<uint4*>(&As[sidx * 8]) = v;
        }
#pragma unroll
        for (int r = 0; r < 2; ++r) {
            int l = tid + r * 256, row = l >> 3, c8 = l & 7;
            int sidx = row * 8 + (c8 ^ (row & 7));
            uint4 v = *reinterpret_cast<const uint4*>(
                &Wt[(size_t)row * 512 + k0 + c8 * 8]);
            *reinterpret_cast<uint4*>(&Bs[sidx * 8]) = v;
        }
        __syncthreads();
#pragma unroll
        for (int kh = 0; kh < 2; ++kh) {
            const int c8r = kh * 4 + (lane >> 4);
            bf16x8 af[2], bfr[4];
#pragma unroll
            for (int m = 0; m < 2; ++m) {
                int rA = wid * 32 + m * 16 + (lane & 15);
                af[m] = *reinterpret_cast<bf16x8*>(
                    &As[rA * 64 + (c8r ^ (rA & 7)) * 8]);
            }
#pragma unroll
            for (int n = 0; n < 4; ++n) {
                int rB = n * 16 + (lane & 15);
                bfr[n] = *reinterpret_cast<bf16x8*>(
                    &Bs[rB * 64 + (c8r ^ (rB & 7)) * 8]);
            }
#pragma unroll
            for (int m = 0; m < 2; ++m)
#pragma unroll
                for (int n = 0; n < 4; ++n)
                    acc[m][n] = __builtin_amdgcn_mfma_f32_16x16x32_bf16(
                        af[m], bfr[n], acc[m][n], 0, 0, 0);
        }
        __syncthreads();
    }
    const int o0 = lane & 15, o1 = 16 + (lane & 15);
    const float bm0 = bmu[o0], bm1 = bmu[o1];
    const float bl0 = blv[o0], bl1 = blv[o1];
#pragma unroll
    for (int m = 0; m < 2; ++m) {
#pragma unroll
        for (int q = 0; q < 4; ++q) {
            int row = bm + wid * 32 + m * 16 + (lane >> 4) * 4 + q;
            float mu0 = acc[m][0][q] + bm0;
            float mu1 = acc[m][1][q] + bm1;
            float lv0 = acc[m][2][q] + bl0;
            float lv1 = acc[m][3][q] + bl1;
            float e0 = eps[(size_t)row * 32 + o0];
            float e1 = eps[(size_t)row * 32 + o1];
            x[(size_t)row * 32 + o0] = mu0 + __expf(0.5f * lv0) * e0;
            x[(size_t)row * 32 + o1] = mu1 + __expf(0.5f * lv1) * e1;
            float pe = (e0 * e0 + lv0) + (e1 * e1 + lv1);
            pe += __shfl_xor(pe, 1, 64);
            pe += __shfl_xor(pe, 2, 64);
            pe += __shfl_xor(pe, 4, 64);
            pe += __shfl_xor(pe, 8, 64);
            if ((lane & 15) == 0)
                xent[row] = 0.5f * (pe + 32.f * LOG2PI);
        }
    }
}

// ---------------------------------------------------------------------------
// K3 (fused): blocks 0-1023: loga; 1024-5115: log_b (t>=1); 5116-5147: log_b0
// ---------------------------------------------------------------------------
__global__ __launch_bounds__(256) void k_lb(
    const float* __restrict__ x, const float* __restrict__ us,
    const float* __restrict__ Wz, const float* __restrict__ bz,
    const float* __restrict__ A, const float* __restrict__ Bu,
    const float* __restrict__ bx, const float* __restrict__ x_logvar,
    const float* __restrict__ x0_mean, const float* __restrict__ x0_logvar,
    float* __restrict__ ap1, float* __restrict__ log_b)
{
    __shared__ float SM[8192 + 256 + 16];
    const int tid = threadIdx.x;
    const int bid = blockIdx.x;
    if (bid < 1024) {
        // ---- loga ----
        float (*xs)[32] = reinterpret_cast<float(*)[32]>(SM);
        const int lane = tid & 63;
        const int wv = tid >> 6;
        const int itemBase = bid * 32;
        {
            int r = tid >> 3, cc = (tid & 7) * 4;
            int item = itemBase + r;
            int src = (item & (NT - 1)) ? item - 1 : item;
            *reinterpret_cast<float4*>(&xs[r][cc]) =
                *reinterpret_cast<const float4*>(&x[(size_t)src * 32 + cc]);
        }
        float wcol[32];
#pragma unroll
        for (int e = 0; e < 32; ++e) wcol[e] = Wz[e * 64 + lane];
        const float bzv = bz[lane];
        __syncthreads();
        const int j = lane >> 3, k = lane & 7;
        for (int i = wv; i < 32; i += 4) {
            int item = itemBase + i;
            if ((item & (NT - 1)) == 0) continue;
            float acc = bzv;
#pragma unroll
            for (int e = 0; e < 32; ++e) acc = fmaf(xs[i][e], wcol[e], acc);
            float lse = lse8_high(acc);
            ap1[(size_t)item * 64 + j * 8 + (j ^ k)] = __expf(acc - lse);
        }
        return;
    }
    if (bid >= 1024 + 4092) {
        // ---- log_b[b][0] ----
        const int b = bid - 5116;
        const int k = tid >> 5, xo = tid & 31;
        float xv = x[((size_t)b * NT) * 32 + xo];
        float mm = x0_mean[k * 32 + xo];
        float lvv = x0_logvar[k * 32 + xo];
        float dd = xv - mm;
        float term = -0.5f * (dd * dd * __expf(-lvv) + lvv + LOG2PI);
        for (int m = 16; m; m >>= 1) term += __shfl_down(term, m, 32);
        if (xo == 0) log_b[(size_t)b * NT * 8 + k] = term;
        return;
    }
    // ---- log_b, 8 items ----
    float* As = SM;
    float (*xs8)[32] = reinterpret_cast<float(*)[32]>(SM + 8192);
    float (*us8)[2] = reinterpret_cast<float(*)[2]>(SM + 8448);
    const int base = (bid - 1024) * 8;
    for (int i = tid; i < 2048; i += 256)
        reinterpret_cast<float4*>(As)[i] =
            reinterpret_cast<const float4*>(A)[i];
    {
        int row = tid >> 5, xo = tid & 31;
        int item = base + row;
        int b = item / 1023, tm = item - b * 1023;
        xs8[row][xo] = x[((size_t)b * NT + tm) * 32 + xo];
        if (xo < 2) us8[row][xo] = us[((size_t)b * NT + tm + 1) * 2 + xo];
    }
    __syncthreads();
    const int k = tid >> 5, xo = tid & 31;
    const float bxv = bx[k * 32 + xo];
    const float bu0 = Bu[(k * 2 + 0) * 32 + xo];
    const float bu1 = Bu[(k * 2 + 1) * 32 + xo];
    const float lvv = x_logvar[k * 32 + xo];
    const float ivv = __expf(-lvv);
    const float basev = lvv + LOG2PI;
    for (int i = 0; i < 8; ++i) {
        int item = base + i;
        int b = item / 1023, tm = item - b * 1023;
        float acc = fmaf(us8[i][0], bu0, fmaf(us8[i][1], bu1, bxv));
#pragma unroll 8
        for (int e = 0; e < 32; ++e)
            acc = fmaf(xs8[i][e], As[k * 1024 + e * 32 + xo], acc);
        float xv = x[((size_t)b * NT + tm + 1) * 32 + xo];
        float dd = xv - acc;
        float term = dd * dd * ivv + basev;
        for (int m = 16; m; m >>= 1) term += __shfl_down(term, m, 32);
        if (xo == 0)
            log_b[((size_t)b * NT + tm + 1) * 8 + k] = -0.5f * term;
    }
}

// ---------------------------------------------------------------------------
// K5a: chunk products; bexp/max computed inline from log_b.
// sA[c] = sum_{t in chunk} max_k(lb_t) + renorm logs.
// ---------------------------------------------------------------------------
__global__ __launch_bounds__(256) void k_fbA(
    const float* __restrict__ ap1, const float* __restrict__ log_b,
    float* __restrict__ Pfx, float* __restrict__ sA)
{
    const int tid = threadIdx.x;
    const int wg = blockIdx.x * 4 + (tid >> 6);
    const int lane = tid & 63;
    const int b = wg / NCH;
    const int c = wg - b * NCH;
    const int j = lane >> 3, k = lane & 7;
    const float* ap = &ap1[(size_t)b * NT * 64];
    const float* lb = &log_b[(size_t)b * NT * 8];
    int t = CHL * c + 1;
    float4 l0 = *reinterpret_cast<const float4*>(&lb[(size_t)t * 8]);
    float4 l1 = *reinterpret_cast<const float4*>(&lb[(size_t)t * 8 + 4]);
    float mm = max8(l0, l1);
    float P = __expf(lb[(size_t)t * 8 + j] - mm) * ap[t * 64 + j * 8 + (j ^ k)];
    float sacc = mm;
    for (int i = 1; i < CHL; ++i) {
        ++t;
        float4 m0 = *reinterpret_cast<const float4*>(&ap[(size_t)t * 64 + j * 8]);
        float4 m1 = *reinterpret_cast<const float4*>(&ap[(size_t)t * 64 + j * 8 + 4]);
        l0 = *reinterpret_cast<const float4*>(&lb[(size_t)t * 8]);
        l1 = *reinterpret_cast<const float4*>(&lb[(size_t)t * 8 + 4]);
        mm = max8(l0, l1);
        float bj = __expf(lb[(size_t)t * 8 + j] - mm);
        sacc += mm;
        float x1 = __shfl_xor(P, 8, 64);
        float x2 = __shfl_xor(P, 16, 64);
        float x3 = __shfl_xor(P, 24, 64);
        float x4 = __shfl_xor(P, 32, 64);
        float x5 = __shfl_xor(P, 40, 64);
        float x6 = __shfl_xor(P, 48, 64);
        float x7 = __shfl_xor(P, 56, 64);
        float c0 = fmaf(m0.y, x1, m0.x * P);
        float c1 = fmaf(m0.w, x3, m0.z * x2);
        float c2 = fmaf(m1.y, x5, m1.x * x4);
        float c3 = fmaf(m1.w, x7, m1.z * x6);
        P = bj * ((c0 + c1) + (c2 + c3));
        if ((i & 3) == 3) {
            float mx = P;
            mx = fmaxf(mx, __shfl_xor(mx, 1, 64));
            mx = fmaxf(mx, __shfl_xor(mx, 2, 64));
            mx = fmaxf(mx, __shfl_xor(mx, 4, 64));
            mx = fmaxf(mx, __shfl_xor(mx, 8, 64));
            mx = fmaxf(mx, __shfl_xor(mx, 16, 64));
            mx = fmaxf(mx, __shfl_xor(mx, 32, 64));
            mx = fmaxf(mx, 1e-30f);
            float r = __builtin_amdgcn_rcpf(mx);
            P *= r;
            sacc -= __logf(r);
        }
    }
    Pfx[((size_t)b * NCH + c) * 64 + j * 8 + (j ^ k)] = P;
    if (lane == 0) sA[b * NCH + c] = sacc;
}

// ---------------------------------------------------------------------------
// K5b: boundary scans over chunk matrices.
// ---------------------------------------------------------------------------
__global__ __launch_bounds__(128) void k_fbB(
    const float* __restrict__ Pfx, const float* __restrict__ sA,
    const float* __restrict__ log_b, const float* __restrict__ log_init_z,
    float* __restrict__ alphaB, float* __restrict__ betaB,
    float* __restrict__ log_px)
{
    const int b = blockIdx.x;
    const int tid = threadIdx.x;
    const int wave = tid >> 6;
    const int lane = tid & 63;
    const int st = lane & 7;
    const float* pf = &Pfx[(size_t)b * NCH * 64];
    if (wave == 0) {
        float liv[8];
        float mz = -1e30f, sz = 0.f;
#pragma unroll
        for (int q = 0; q < 8; ++q) liv[q] = log_init_z[q];
#pragma unroll
        for (int q = 0; q < 8; ++q) mz = fmaxf(mz, liv[q]);
#pragma unroll
        for (int q = 0; q < 8; ++q) sz += __expf(liv[q] - mz);
        const float* lb0 = &log_b[(size_t)b * NT * 8];
        float4 l0 = *reinterpret_cast<const float4*>(lb0);
        float4 l1 = *reinterpret_cast<const float4*>(lb0 + 4);
        float mb0 = max8(l0, l1);
        float alpha = (__expf(liv[st] - mz) / sz) * __expf(lb0[st] - mb0);
        float logS = 0.f, sAsum = 0.f;
        {
            float s = fmaxf(gsum8(alpha), 1e-35f);
            logS += __logf(s);
            alpha *= __builtin_amdgcn_rcpf(s);
        }
        if (lane < 8) alphaB[((size_t)b * (NCH + 1)) * 8 + lane] = alpha;
        for (int c = 0; c < NCH; ++c) {
            float4 a0 = *reinterpret_cast<const float4*>(&pf[(size_t)c * 64 + st * 8]);
            float4 a1 = *reinterpret_cast<const float4*>(&pf[(size_t)c * 64 + st * 8 + 4]);
            alpha = fb_matvec(a0, a1, alpha);
            float s = fmaxf(gsum8(alpha), 1e-35f);
            logS += __logf(s);
            alpha *= __builtin_amdgcn_rcpf(s);
            sAsum += sA[b * NCH + c];
            if (lane < 8) alphaB[((size_t)b * (NCH + 1) + c + 1) * 8 + lane] = alpha;
        }
        if (lane == 0) log_px[b] = mb0 + sAsum + logS;
    } else {
        float beta = 1.f;
        if (lane < 8) betaB[((size_t)b * (NCH + 1) + NCH) * 8 + lane] = 1.f;
        for (int c = NCH - 1; c >= 0; --c) {
            float4 a0 = *reinterpret_cast<const float4*>(&pf[(size_t)c * 64 + st * 8]);
            float4 a1 = *reinterpret_cast<const float4*>(&pf[(size_t)c * 64 + st * 8 + 4]);
            beta = fb_matvecT(a0, a1, beta);
            float s = fmaxf(gsum8(beta), 1e-35f);
            beta *= __builtin_amdgcn_rcpf(s);
            if (lane < 8) betaB[((size_t)b * (NCH + 1) + c) * 8 + lane] = beta;
        }
    }
}

// ---------------------------------------------------------------------------
// K5c: within-chunk recompute + gamma; bexp inline (per-t scale cancels).
// ---------------------------------------------------------------------------
__global__ __launch_bounds__(256) void k_fbC(
    const float* __restrict__ ap1, const float* __restrict__ log_b,
    const float* __restrict__ alphaB, const float* __restrict__ betaB,
    float* __restrict__ gamma)
{
    __shared__ float alphaS[32][CHL][8];
    const int tid = threadIdx.x;
    const int g = tid >> 3;
    const int st = tid & 7;
    const int task = blockIdx.x * 32 + g;
    const int b = task / NCH;
    const int c = task - b * NCH;
    const float* ap = &ap1[(size_t)b * NT * 64];
    const float* lb = &log_b[(size_t)b * NT * 8];
    const int t0 = CHL * c;
    float alpha = alphaB[((size_t)b * (NCH + 1) + c) * 8 + st];
#pragma unroll
    for (int i = 1; i <= CHL; ++i) {
        int t = t0 + i;
        float4 a0 = *reinterpret_cast<const float4*>(&ap[(size_t)t * 64 + st * 8]);
        float4 a1 = *reinterpret_cast<const float4*>(&ap[(size_t)t * 64 + st * 8 + 4]);
        float4 l0 = *reinterpret_cast<const float4*>(&lb[(size_t)t * 8]);
        float4 l1 = *reinterpret_cast<const float4*>(&lb[(size_t)t * 8 + 4]);
        float bv = __expf(lb[(size_t)t * 8 + st] - max8(l0, l1));
        alpha = fb_matvec(a0, a1, alpha) * bv;
        if (i == 5)
            alpha *= __builtin_amdgcn_rcpf(fmaxf(gsum8(alpha), 1e-35f));
        alphaS[g][i - 1][st] = alpha;
    }
    float beta = betaB[((size_t)b * (NCH + 1) + c + 1) * 8 + st];
#pragma unroll
    for (int i = CHL; i >= 1; --i) {
        int t = t0 + i;
        float gv = alphaS[g][i - 1][st] * beta;
        float s = fmaxf(gsum8(gv), 1e-35f);
        gamma[((size_t)b * NT + t) * 8 + st] = gv * __builtin_amdgcn_rcpf(s);
        float4 a0 = *reinterpret_cast<const float4*>(&ap[(size_t)t * 64 + st * 8]);
        float4 a1 = *reinterpret_cast<const float4*>(&ap[(size_t)t * 64 + st * 8 + 4]);
        float4 l0 = *reinterpret_cast<const float4*>(&lb[(size_t)t * 8]);
        float4 l1 = *reinterpret_cast<const float4*>(&lb[(size_t)t * 8 + 4]);
        float bv = __expf(lb[(size_t)t * 8 + st] - max8(l0, l1));
        beta = fb_matvecT(a0, a1, beta * bv);
        if (i == 6)
            beta *= __builtin_amdgcn_rcpf(fmaxf(gsum8(beta), 1e-35f));
    }
    if (c == 0) {
        float a0v = alphaB[((size_t)b * (NCH + 1)) * 8 + st];
        float gv = a0v * beta;
        float s = fmaxf(gsum8(gv), 1e-35f);
        gamma[((size_t)b * NT) * 8 + st] = gv * __builtin_amdgcn_rcpf(s);
    }
}

// ---------------------------------------------------------------------------
// K6: emission via recomputed gamma-mixed mean + factorized quadratic form.
// ---------------------------------------------------------------------------
__global__ __launch_bounds__(256) void k_py(
    const float* __restrict__ x, const float* __restrict__ us,
    const float* __restrict__ A, const float* __restrict__ Bu,
    const float* __restrict__ bx, const float* __restrict__ gamma,
    const float* __restrict__ proj, const float* __restrict__ term1,
    const float* __restrict__ Gm, const float* __restrict__ c2x,
    const float* __restrict__ xent, float* __restrict__ red)
{
    __shared__ float As[8192];
    __shared__ float Gs[32 * 33];
    __shared__ float c2s[32];
    __shared__ float xp8[8][32];
    __shared__ float gs[8][8];
    __shared__ float us8[8][2];
    __shared__ float xgS[8][32];
    const int tid = threadIdx.x;
    const int itemBase = blockIdx.x * 8;
    const int t0 = itemBase & (NT - 1);
    for (int i = tid; i < 2048; i += 256)
        reinterpret_cast<float4*>(As)[i] =
            reinterpret_cast<const float4*>(A)[i];
    for (int i = tid; i < 32 * 33; i += 256) Gs[i] = Gm[i];
    if (tid < 32) c2s[tid] = c2x[tid];
    {
        int it = tid >> 5, xo = tid & 31;
        int t = t0 + it;
        int item = itemBase + it;
        xp8[it][xo] = (t > 0) ? x[((size_t)item - 1) * 32 + xo] : 0.f;
        if (xo < 8) gs[it][xo] = (t > 0) ? gamma[(size_t)item * 8 + xo] : 0.f;
        if (xo < 2) us8[it][xo] = (t > 0) ? us[(size_t)item * 2 + xo] : 0.f;
    }
    __syncthreads();
    const int it = tid >> 5;
    const int xo = tid & 31;
    const int t = t0 + it;
    const int item = itemBase + it;
    float xg;
    if (t == 0) {
        xg = x[(size_t)item * 32 + xo];
    } else {
        xg = 0.f;
#pragma unroll
        for (int k = 0; k < 8; ++k) {
            float acc = bx[k * 32 + xo];
            acc = fmaf(us8[it][0], Bu[(k * 2 + 0) * 32 + xo], acc);
            acc = fmaf(us8[it][1], Bu[(k * 2 + 1) * 32 + xo], acc);
#pragma unroll 8
            for (int e = 0; e < 32; ++e)
                acc = fmaf(xp8[it][e], As[k * 1024 + e * 32 + xo], acc);
            xg = fmaf(gs[it][k], acc, xg);
        }
    }
    xgS[it][xo] = xg;
    __syncthreads();
    float gmv = 0.f;
#pragma unroll 8
    for (int y = 0; y < 32; ++y)
        gmv = fmaf(Gs[xo * 33 + y], xgS[it][y], gmv);
    float val = xg * (proj[(size_t)item * 32 + xo] - c2s[xo] - 0.5f * gmv);
    val += __shfl_xor(val, 1, 64);
    val += __shfl_xor(val, 2, 64);
    val += __shfl_xor(val, 4, 64);
    val += __shfl_xor(val, 8, 64);
    val += __shfl_xor(val, 16, 64);
    if (xo == 0)
        red[item] = -0.5f * term1[item] + val + xent[item];
}

// ---------------------------------------------------------------------------
// K7: elbo = (sum red + sum log_px)/NB - 512*sum(ylv+LOG2PI)
// ---------------------------------------------------------------------------
__global__ __launch_bounds__(256) void k_final(
    const float* __restrict__ red, const float* __restrict__ log_px,
    const float* __restrict__ ylv, float* __restrict__ out)
{
    __shared__ float ssum[4];
    __shared__ float ssum2[4];
    const int tid = threadIdx.x;
    float s = 0.f, t = 0.f;
    for (int i = tid; i < NB * NT; i += 256) s += red[i];
    if (tid < NB) s += log_px[tid];
    for (int i = tid; i < 512; i += 256) t += ylv[i] + LOG2PI;
#pragma unroll
    for (int m = 1; m < 64; m <<= 1) {
        s += __shfl_xor(s, m, 64);
        t += __shfl_xor(t, m, 64);
    }
    if ((tid & 63) == 0) { ssum[tid >> 6] = s; ssum2[tid >> 6] = t; }
    __syncthreads();
    if (tid == 0) {
        float S = ssum[0] + ssum[1] + ssum[2] + ssum[3];
        float T = ssum2[0] + ssum2[1] + ssum2[2] + ssum2[3];
        out[0] = S / (float)NB - 512.0f * T;
    }
}

// ---------------------------------------------------------------------------
extern "C" void kernel_launch(void* const* d_in, const int* in_sizes, int n_in,
                              void* d_out, int out_size, void* d_ws,
                              size_t ws_size, hipStream_t stream)
{
    const float* ys        = (const float*)d_in[0];
    const float* us        = (const float*)d_in[1];
    const float* eps       = (const float*)d_in[2];
    const float* W1        = (const float*)d_in[3];
    const float* b1        = (const float*)d_in[4];
    const float* Wmu       = (const float*)d_in[5];
    const float* bmu       = (const float*)d_in[6];
    const float* Wlv       = (const float*)d_in[7];
    const float* blv       = (const float*)d_in[8];
    const float* Wz        = (const float*)d_in[9];
    const float* bz        = (const float*)d_in[10];
    const float* A         = (const float*)d_in[11];
    const float* Bu        = (const float*)d_in[12];
    const float* bx        = (const float*)d_in[13];
    const float* x_logvar  = (const float*)d_in[14];
    const float* x0_mean   = (const float*)d_in[15];
    const float* x0_logvar = (const float*)d_in[16];
    const float* C         = (const float*)d_in[17];
    const float* dv        = (const float*)d_in[18];
    const float* y_logvar  = (const float*)d_in[19];
    const float* log_init_z= (const float*)d_in[20];
    float* out = (float*)d_out;

    float* ws = (float*)d_ws;
    float* x      = ws;                    //  1,048,576
    float* xent   = x + 1048576;           //     32,768
    float* ap1    = xent + 32768;          //  2,097,152
    float* log_b  = ap1 + 2097152;         //    262,144
    float* gam    = log_b + 262144;        //    262,144
    float* log_px = gam + 262144;          //         32
    float* red    = log_px + 32;           //     32,768
    float* hbf_f  = red + 32768;           //  8,388,608 (h bf16)
    float* w1t_f  = hbf_f + 8388608;       //    131,072 (W1^T bf16)
    float* wmlv_f = w1t_f + 131072;        //     16,384 (Wmu|Wlv^T bf16)
    float* proj   = wmlv_f + 16384;        //  1,048,576
    float* term1  = proj + 1048576;        //     32,768
    float* ivbuf  = term1 + 32768;         //        512
    float* w2bf_f = ivbuf + 512;           //      8,192 (W2 bf16)
    float* Gm     = w2bf_f + 8192;         //      1,056
    float* c2x    = Gm + 1056;             //         32
    float* Pfx    = c2x + 32;              //    190,464
    float* sA     = Pfx + 190464;          //      2,976
    float* alphaB = sA + 2976;             //     24,064
    float* betaB  = alphaB + 24064;        //     24,064

    unsigned short* hbf  = (unsigned short*)hbf_f;
    unsigned short* w1t  = (unsigned short*)w1t_f;
    unsigned short* wmlv = (unsigned short*)wmlv_f;
    unsigned short* w2bf = (unsigned short*)w2bf_f;

    k_prep_w <<<321, 256, 0, stream>>>(W1, Wmu, Wlv, C, dv, y_logvar,
                                       w1t, wmlv, w2bf, Gm, c2x, ivbuf);
    k_gemm_h_mfma<<<1024, 256, 0, stream>>>(ys, w1t, w2bf, b1, dv, ivbuf,
                                            hbf, proj, term1);
    k_mulv_mfma<<<256, 256, 0, stream>>>(hbf, wmlv, bmu, blv, eps, x, xent);
    k_lb     <<<5148, 256, 0, stream>>>(x, us, Wz, bz, A, Bu, bx, x_logvar,
                                        x0_mean, x0_logvar, ap1, log_b);
    k_fbA    <<<744, 256, 0, stream>>>(ap1, log_b, Pfx, sA);
    k_fbB    <<<32, 128, 0, stream>>>(Pfx, sA, log_b, log_init_z,
                                      alphaB, betaB, log_px);
    k_fbC    <<<93, 256, 0, stream>>>(ap1, log_b, alphaB, betaB, gam);
    k_py     <<<4096, 256, 0, stream>>>(x, us, A, Bu, bx, gam, proj, term1,
                                        Gm, c2x, xent, red);
    k_final  <<<1, 256, 0, stream>>>(red, log_px, y_logvar, out);
}

// Round 11
// 250.484 us; speedup vs baseline: 1.8514x; 1.4249x over previous
//
#include <hip/hip_runtime.h>
#include <math.h>

#define LOG2PI 1.8378770664093453f

// Problem sizes (fixed)
#define NB 32
#define NT 1024
#define ND 512
#define NH 512
#define NX 32
#define NK 8
#define NU 2

// chunked scan: 1023 transitions = 93 chunks x 11
#define NCH 93
#define CHL 11

typedef __attribute__((ext_vector_type(8))) short bf16x8;
typedef __attribute__((ext_vector_type(4))) float f32x4;

__device__ __forceinline__ unsigned short f2bf(float f) {
    unsigned u = __float_as_uint(f);
    unsigned r = (u + 0x7FFF + ((u >> 16) & 1)) >> 16;
    return (unsigned short)r;
}

// pack two f32 -> two bf16 (round-half-up): 2 adds + 1 v_perm
__device__ __forceinline__ unsigned pack_bf2(float a, float b) {
    unsigned ua = __float_as_uint(a) + 0x8000u;
    unsigned ub = __float_as_uint(b) + 0x8000u;
    return __builtin_amdgcn_perm(ub, ua, 0x07060302);
}

// fast tanh: 1 - 2/(e^{2x}+1)
__device__ __forceinline__ float tanh_fast(float v) {
    float t = __expf(2.0f * v);
    return 1.0f - 2.0f * __builtin_amdgcn_rcpf(t + 1.0f);
}

// ---------------------------------------------------------------------------
// DPP xor-shuffles within 8-lane groups
// ---------------------------------------------------------------------------
#define DPP_X1 0xB1
#define DPP_X2 0x4E
#define DPP_X3 0x1B
#define DPP_X7 0x141

template <int CTRL>
__device__ __forceinline__ float dppx(float v) {
    return __int_as_float(__builtin_amdgcn_update_dpp(
        0, __float_as_int(v), CTRL, 0xF, 0xF, true));
}

__device__ __forceinline__ float fb_matvec(float4 a0, float4 a1, float v) {
    float p1 = dppx<DPP_X1>(v);
    float p2 = dppx<DPP_X2>(v);
    float p3 = dppx<DPP_X3>(v);
    float p7 = dppx<DPP_X7>(v);
    float p4 = dppx<DPP_X7>(p3);
    float p5 = dppx<DPP_X7>(p2);
    float p6 = dppx<DPP_X7>(p1);
    float c0 = fmaf(a0.y, p1, a0.x * v);
    float c1 = fmaf(a0.w, p3, a0.z * p2);
    float c2 = fmaf(a1.y, p5, a1.x * p4);
    float c3 = fmaf(a1.w, p7, a1.z * p6);
    return (c0 + c1) + (c2 + c3);
}

__device__ __forceinline__ float fb_matvecT(float4 a0, float4 a1, float w) {
    float q0 = a0.x * w;
    float t1 = dppx<DPP_X1>(a0.y * w);
    float t2 = dppx<DPP_X2>(a0.z * w);
    float t3 = dppx<DPP_X3>(a0.w * w);
    float t7 = dppx<DPP_X7>(a1.w * w);
    float t4 = dppx<DPP_X7>(dppx<DPP_X3>(a1.x * w));
    float t5 = dppx<DPP_X7>(dppx<DPP_X2>(a1.y * w));
    float t6 = dppx<DPP_X7>(dppx<DPP_X1>(a1.z * w));
    return ((q0 + t1) + (t2 + t3)) + ((t4 + t5) + (t6 + t7));
}

__device__ __forceinline__ float gsum8(float v) {
    float s = v + dppx<DPP_X1>(v);
    s = s + dppx<DPP_X2>(s);
    s = s + dppx<DPP_X7>(dppx<DPP_X3>(s));
    return s;
}

// max over 8 consecutive floats held as two float4
__device__ __forceinline__ float max8(float4 l0, float4 l1) {
    return fmaxf(fmaxf(fmaxf(l0.x, l0.y), fmaxf(l0.z, l0.w)),
                 fmaxf(fmaxf(l1.x, l1.y), fmaxf(l1.z, l1.w)));
}

__device__ __forceinline__ float lse8_high(float v) {
    float m = v;
    m = fmaxf(m, __shfl_xor(m, 8, 64));
    m = fmaxf(m, __shfl_xor(m, 16, 64));
    m = fmaxf(m, __shfl_xor(m, 32, 64));
    float s = __expf(v - m);
    s += __shfl_xor(s, 8, 64);
    s += __shfl_xor(s, 16, 64);
    s += __shfl_xor(s, 32, 64);
    return m + __logf(s);
}

// ---------------------------------------------------------------------------
// K_prep_w: merged weight prep.
//   blocks 0-255   : W1 -> W1T bf16
//   blocks 256-287 : Wmu/Wlv -> wmlv [64][512] bf16
//   blocks 288-319 : G[x][y] + c2x[x]
//   block  320     : W2bf = bf16(exp(-ylv)*C), ivbuf = exp(-ylv)
// ---------------------------------------------------------------------------
__global__ __launch_bounds__(256) void k_prep_w(
    const float* __restrict__ W1, const float* __restrict__ Wmu,
    const float* __restrict__ Wlv, const float* __restrict__ C,
    const float* __restrict__ dvec, const float* __restrict__ ylv,
    unsigned short* __restrict__ WT, unsigned short* __restrict__ wmlv,
    unsigned short* __restrict__ W2bf, float* __restrict__ G,
    float* __restrict__ c2x, float* __restrict__ ivbuf)
{
    __shared__ float tile[32][33];
    const int bid = blockIdx.x;
    const int tid = threadIdx.x;
    if (bid < 256) {
        const int bx = (bid & 15) * 32;
        const int by = (bid >> 4) * 32;
        const int tx = tid & 31, ty = tid >> 5;
        for (int i = ty; i < 32; i += 8)
            tile[i][tx] = W1[(size_t)(bx + i) * 512 + by + tx];
        __syncthreads();
        for (int i = ty; i < 32; i += 8)
            WT[(size_t)(by + i) * 512 + bx + tx] = f2bf(tile[tx][i]);
        return;
    }
    if (bid < 288) {
        const int t = bid - 256;
        const float* W = (t >> 4) ? Wlv : Wmu;
        const int base = (t >> 4) * 32;
        const int g = t & 15;
        const int tx = tid & 31, ty = tid >> 5;
        for (int i = ty; i < 32; i += 8)
            tile[i][tx] = W[(size_t)(g * 32 + i) * 32 + tx];
        __syncthreads();
        for (int i = ty; i < 32; i += 8)
            wmlv[(size_t)(base + i) * 512 + g * 32 + tx] = f2bf(tile[tx][i]);
        return;
    }
    if (bid == 320) {
        for (int i = tid; i < 32 * 512; i += 256)
            W2bf[i] = f2bf(C[i] * __expf(-ylv[i & 511]));
        ivbuf[tid] = __expf(-ylv[tid]);
        ivbuf[tid + 256] = __expf(-ylv[tid + 256]);
        return;
    }
    const int x = bid - 288;
    const int y = tid >> 3, seg = tid & 7;
    const float* Cx = &C[(size_t)x * 512];
    const float* Cy = &C[(size_t)y * 512];
    float p = 0.f;
    for (int j = 0; j < 64; ++j) {
        int dcol = seg * 64 + j;
        p = fmaf(Cx[dcol] * __expf(-ylv[dcol]), Cy[dcol], p);
    }
    p = gsum8(p);
    if (seg == 0) G[x * 33 + y] = p;
    if (tid < 8) {
        float q = 0.f;
        for (int j = 0; j < 64; ++j) {
            int dcol = tid * 64 + j;
            q = fmaf(Cx[dcol] * __expf(-ylv[dcol]), dvec[dcol], q);
        }
        q = gsum8(q);
        if (tid == 0) c2x[x] = q;
    }
}

// ---------------------------------------------------------------------------
// K1 (R6-proven): h = bf16(tanh(ys@W1+b1)), 128x128 tile, f32 ys staged with
// inline cast. Grid dim3(256,4): bm = blockIdx.x (x-major dispatch), bn = y.
// ---------------------------------------------------------------------------
__global__ __launch_bounds__(256) void k_gemm_h_mfma(
    const float* __restrict__ ys,
    const unsigned short* __restrict__ Bbf,   // W1T [512][512] bf16
    const float* __restrict__ b1, unsigned short* __restrict__ hb)
{
    __shared__ unsigned short As[128 * 64];
    __shared__ unsigned short Bs[128 * 64];
    const int tid = threadIdx.x;
    const int bm = blockIdx.x * 128;
    const int bn = blockIdx.y * 128;
    const int wid = tid >> 6, lane = tid & 63;
    const int wm = wid >> 1, wn = wid & 1;

    f32x4 acc[4][4];
#pragma unroll
    for (int m = 0; m < 4; ++m)
#pragma unroll
        for (int n = 0; n < 4; ++n)
            acc[m][n] = (f32x4){0.f, 0.f, 0.f, 0.f};

    for (int k0 = 0; k0 < 512; k0 += 64) {
#pragma unroll
        for (int r = 0; r < 4; ++r) {
            int l = tid + r * 256;
            int row = l >> 3, c8 = l & 7;
            int sidx = row * 8 + (c8 ^ (row & 7));
            const float4 f0 = *reinterpret_cast<const float4*>(
                &ys[(size_t)(bm + row) * 512 + k0 + c8 * 8]);
            const float4 f1 = *reinterpret_cast<const float4*>(
                &ys[(size_t)(bm + row) * 512 + k0 + c8 * 8 + 4]);
            uint4 ua;
            ua.x = pack_bf2(f0.x, f0.y);
            ua.y = pack_bf2(f0.z, f0.w);
            ua.z = pack_bf2(f1.x, f1.y);
            ua.w = pack_bf2(f1.z, f1.w);
            *reinterpret_cast<uint4*>(&As[sidx * 8]) = ua;
            uint4 vb = *reinterpret_cast<const uint4*>(
                &Bbf[(size_t)(bn + row) * 512 + k0 + c8 * 8]);
            *reinterpret_cast<uint4*>(&Bs[sidx * 8]) = vb;
        }
        __syncthreads();
#pragma unroll
        for (int kh = 0; kh < 2; ++kh) {
            bf16x8 af[4], bfr[4];
            const int c8r = kh * 4 + (lane >> 4);
#pragma unroll
            for (int m = 0; m < 4; ++m) {
                int rA = wm * 64 + m * 16 + (lane & 15);
                af[m] = *reinterpret_cast<bf16x8*>(
                    &As[rA * 64 + (c8r ^ (rA & 7)) * 8]);
            }
#pragma unroll
            for (int n = 0; n < 4; ++n) {
                int rB = wn * 64 + n * 16 + (lane & 15);
                bfr[n] = *reinterpret_cast<bf16x8*>(
                    &Bs[rB * 64 + (c8r ^ (rB & 7)) * 8]);
            }
#pragma unroll
            for (int m = 0; m < 4; ++m)
#pragma unroll
                for (int n = 0; n < 4; ++n)
                    acc[m][n] = __builtin_amdgcn_mfma_f32_16x16x32_bf16(
                        af[m], bfr[n], acc[m][n], 0, 0, 0);
        }
        __syncthreads();
    }
    float b1v[4];
#pragma unroll
    for (int n = 0; n < 4; ++n)
        b1v[n] = b1[bn + wn * 64 + n * 16 + (lane & 15)];
#pragma unroll
    for (int m = 0; m < 4; ++m) {
#pragma unroll
        for (int q = 0; q < 4; ++q) {
            int row = bm + wm * 64 + m * 16 + (lane >> 4) * 4 + q;
#pragma unroll
            for (int n = 0; n < 4; ++n) {
                int col = bn + wn * 64 + n * 16 + (lane & 15);
                hb[(size_t)row * 512 + col] =
                    f2bf(tanh_fast(acc[m][n][q] + b1v[n]));
            }
        }
    }
}

// ---------------------------------------------------------------------------
// K2b (R6-proven): proj = ys @ W2bf^T (f32 ys, inline cast) + fused term1.
// ---------------------------------------------------------------------------
__global__ __launch_bounds__(256) void k_proj(
    const float* __restrict__ ys, const unsigned short* __restrict__ W2bf,
    const float* __restrict__ dvec, const float* __restrict__ ivbuf,
    float* __restrict__ proj, float* __restrict__ term1)
{
    __shared__ unsigned short As[128 * 64];
    __shared__ unsigned short Bs[32 * 64];
    const int tid = threadIdx.x;
    const int bm = blockIdx.x * 128;
    const int wid = tid >> 6, lane = tid & 63;
    const int c8 = tid & 7;
    f32x4 acc[2][2];
#pragma unroll
    for (int m = 0; m < 2; ++m)
#pragma unroll
        for (int n = 0; n < 2; ++n)
            acc[m][n] = (f32x4){0.f, 0.f, 0.f, 0.f};
    float t1p[4] = {0.f, 0.f, 0.f, 0.f};

    for (int k0 = 0; k0 < 512; k0 += 64) {
        const float4 dv0 = *reinterpret_cast<const float4*>(&dvec[k0 + c8 * 8]);
        const float4 dv1 = *reinterpret_cast<const float4*>(&dvec[k0 + c8 * 8 + 4]);
        const float4 iv0 = *reinterpret_cast<const float4*>(&ivbuf[k0 + c8 * 8]);
        const float4 iv1 = *reinterpret_cast<const float4*>(&ivbuf[k0 + c8 * 8 + 4]);
#pragma unroll
        for (int r = 0; r < 4; ++r) {
            int l = tid + r * 256;
            int row = l >> 3;
            int sidx = row * 8 + (c8 ^ (row & 7));
            const float4 f0 = *reinterpret_cast<const float4*>(
                &ys[(size_t)(bm + row) * 512 + k0 + c8 * 8]);
            const float4 f1 = *reinterpret_cast<const float4*>(
                &ys[(size_t)(bm + row) * 512 + k0 + c8 * 8 + 4]);
            float g0 = f0.x - dv0.x, g1 = f0.y - dv0.y;
            float g2 = f0.z - dv0.z, g3 = f0.w - dv0.w;
            float g4 = f1.x - dv1.x, g5 = f1.y - dv1.y;
            float g6 = f1.z - dv1.z, g7 = f1.w - dv1.w;
            t1p[r] += (g0 * g0 * iv0.x + g1 * g1 * iv0.y)
                    + (g2 * g2 * iv0.z + g3 * g3 * iv0.w)
                    + (g4 * g4 * iv1.x + g5 * g5 * iv1.y)
                    + (g6 * g6 * iv1.z + g7 * g7 * iv1.w);
            uint4 ua;
            ua.x = pack_bf2(f0.x, f0.y);
            ua.y = pack_bf2(f0.z, f0.w);
            ua.z = pack_bf2(f1.x, f1.y);
            ua.w = pack_bf2(f1.z, f1.w);
            *reinterpret_cast<uint4*>(&As[sidx * 8]) = ua;
        }
        {
            int row = tid >> 3;
            int sidx = row * 8 + (c8 ^ (row & 7));
            uint4 v = *reinterpret_cast<const uint4*>(
                &W2bf[(size_t)row * 512 + k0 + c8 * 8]);
            *reinterpret_cast<uint4*>(&Bs[sidx * 8]) = v;
        }
        __syncthreads();
#pragma unroll
        for (int kh = 0; kh < 2; ++kh) {
            const int c8r = kh * 4 + (lane >> 4);
            bf16x8 af[2], bfr[2];
#pragma unroll
            for (int m = 0; m < 2; ++m) {
                int rA = wid * 32 + m * 16 + (lane & 15);
                af[m] = *reinterpret_cast<bf16x8*>(
                    &As[rA * 64 + (c8r ^ (rA & 7)) * 8]);
            }
#pragma unroll
            for (int n = 0; n < 2; ++n) {
                int rB = n * 16 + (lane & 15);
                bfr[n] = *reinterpret_cast<bf16x8*>(
                    &Bs[rB * 64 + (c8r ^ (rB & 7)) * 8]);
            }
#pragma unroll
            for (int m = 0; m < 2; ++m)
#pragma unroll
                for (int n = 0; n < 2; ++n)
                    acc[m][n] = __builtin_amdgcn_mfma_f32_16x16x32_bf16(
                        af[m], bfr[n], acc[m][n], 0, 0, 0);
        }
        __syncthreads();
    }
#pragma unroll
    for (int m = 0; m < 2; ++m)
#pragma unroll
        for (int q = 0; q < 4; ++q) {
            int row = bm + wid * 32 + m * 16 + (lane >> 4) * 4 + q;
#pragma unroll
            for (int n = 0; n < 2; ++n) {
                int col = n * 16 + (lane & 15);
                proj[(size_t)row * 32 + col] = acc[m][n][q];
            }
        }
#pragma unroll
    for (int r = 0; r < 4; ++r) {
        float s = gsum8(t1p[r]);
        if ((tid & 7) == 0) term1[bm + (tid >> 3) + r * 32] = s;
    }
}

// ---------------------------------------------------------------------------
// K2: [mu|lv] = h_bf @ Wt^T via MFMA; epilogue fuses x, xent
// ---------------------------------------------------------------------------
__global__ __launch_bounds__(256) void k_mulv_mfma(
    const unsigned short* __restrict__ hbf,
    const unsigned short* __restrict__ Wt,
    const float* __restrict__ bmu, const float* __restrict__ blv,
    const float* __restrict__ eps,
    float* __restrict__ x, float* __restrict__ xent)
{
    __shared__ unsigned short As[128 * 64];
    __shared__ unsigned short Bs[64 * 64];
    const int tid = threadIdx.x;
    const int bm = blockIdx.x * 128;
    const int wid = tid >> 6, lane = tid & 63;
    f32x4 acc[2][4];
#pragma unroll
    for (int m = 0; m < 2; ++m)
#pragma unroll
        for (int n = 0; n < 4; ++n)
            acc[m][n] = (f32x4){0.f, 0.f, 0.f, 0.f};

    for (int k0 = 0; k0 < 512; k0 += 64) {
#pragma unroll
        for (int r = 0; r < 4; ++r) {
            int l = tid + r * 256, row = l >> 3, c8 = l & 7;
            int sidx = row * 8 + (c8 ^ (row & 7));
            uint4 v = *reinterpret_cast<const uint4*>(
                &hbf[(size_t)(bm + row) * 512 + k0 + c8 * 8]);
            *reinterpret_cast<uint4*>(&As[sidx * 8]) = v;
        }
#pragma unroll
        for (int r = 0; r < 2; ++r) {
            int l = tid + r * 256, row = l >> 3, c8 = l & 7;
            int sidx = row * 8 + (c8 ^ (row & 7));
            uint4 v = *reinterpret_cast<const uint4*>(
                &Wt[(size_t)row * 512 + k0 + c8 * 8]);
            *reinterpret_cast<uint4*>(&Bs[sidx * 8]) = v;
        }
        __syncthreads();
#pragma unroll
        for (int kh = 0; kh < 2; ++kh) {
            const int c8r = kh * 4 + (lane >> 4);
            bf16x8 af[2], bfr[4];
#pragma unroll
            for (int m = 0; m < 2; ++m) {
                int rA = wid * 32 + m * 16 + (lane & 15);
                af[m] = *reinterpret_cast<bf16x8*>(
                    &As[rA * 64 + (c8r ^ (rA & 7)) * 8]);
            }
#pragma unroll
            for (int n = 0; n < 4; ++n) {
                int rB = n * 16 + (lane & 15);
                bfr[n] = *reinterpret_cast<bf16x8*>(
                    &Bs[rB * 64 + (c8r ^ (rB & 7)) * 8]);
            }
#pragma unroll
            for (int m = 0; m < 2; ++m)
#pragma unroll
                for (int n = 0; n < 4; ++n)
                    acc[m][n] = __builtin_amdgcn_mfma_f32_16x16x32_bf16(
                        af[m], bfr[n], acc[m][n], 0, 0, 0);
        }
        __syncthreads();
    }
    const int o0 = lane & 15, o1 = 16 + (lane & 15);
    const float bm0 = bmu[o0], bm1 = bmu[o1];
    const float bl0 = blv[o0], bl1 = blv[o1];
#pragma unroll
    for (int m = 0; m < 2; ++m) {
#pragma unroll
        for (int q = 0; q < 4; ++q) {
            int row = bm + wid * 32 + m * 16 + (lane >> 4) * 4 + q;
            float mu0 = acc[m][0][q] + bm0;
            float mu1 = acc[m][1][q] + bm1;
            float lv0 = acc[m][2][q] + bl0;
            float lv1 = acc[m][3][q] + bl1;
            float e0 = eps[(size_t)row * 32 + o0];
            float e1 = eps[(size_t)row * 32 + o1];
            x[(size_t)row * 32 + o0] = mu0 + __expf(0.5f * lv0) * e0;
            x[(size_t)row * 32 + o1] = mu1 + __expf(0.5f * lv1) * e1;
            float pe = (e0 * e0 + lv0) + (e1 * e1 + lv1);
            pe += __shfl_xor(pe, 1, 64);
            pe += __shfl_xor(pe, 2, 64);
            pe += __shfl_xor(pe, 4, 64);
            pe += __shfl_xor(pe, 8, 64);
            if ((lane & 15) == 0)
                xent[row] = 0.5f * (pe + 32.f * LOG2PI);
        }
    }
}

// ---------------------------------------------------------------------------
// K3 (fused): blocks 0-1023: loga; 1024-5115: log_b (t>=1); 5116-5147: log_b0
// ---------------------------------------------------------------------------
__global__ __launch_bounds__(256) void k_lb(
    const float* __restrict__ x, const float* __restrict__ us,
    const float* __restrict__ Wz, const float* __restrict__ bz,
    const float* __restrict__ A, const float* __restrict__ Bu,
    const float* __restrict__ bx, const float* __restrict__ x_logvar,
    const float* __restrict__ x0_mean, const float* __restrict__ x0_logvar,
    float* __restrict__ ap1, float* __restrict__ log_b)
{
    __shared__ float SM[8192 + 256 + 16];
    const int tid = threadIdx.x;
    const int bid = blockIdx.x;
    if (bid < 1024) {
        // ---- loga ----
        float (*xs)[32] = reinterpret_cast<float(*)[32]>(SM);
        const int lane = tid & 63;
        const int wv = tid >> 6;
        const int itemBase = bid * 32;
        {
            int r = tid >> 3, cc = (tid & 7) * 4;
            int item = itemBase + r;
            int src = (item & (NT - 1)) ? item - 1 : item;
            *reinterpret_cast<float4*>(&xs[r][cc]) =
                *reinterpret_cast<const float4*>(&x[(size_t)src * 32 + cc]);
        }
        float wcol[32];
#pragma unroll
        for (int e = 0; e < 32; ++e) wcol[e] = Wz[e * 64 + lane];
        const float bzv = bz[lane];
        __syncthreads();
        const int j = lane >> 3, k = lane & 7;
        for (int i = wv; i < 32; i += 4) {
            int item = itemBase + i;
            if ((item & (NT - 1)) == 0) continue;
            float acc = bzv;
#pragma unroll
            for (int e = 0; e < 32; ++e) acc = fmaf(xs[i][e], wcol[e], acc);
            float lse = lse8_high(acc);
            ap1[(size_t)item * 64 + j * 8 + (j ^ k)] = __expf(acc - lse);
        }
        return;
    }
    if (bid >= 1024 + 4092) {
        // ---- log_b[b][0] ----
        const int b = bid - 5116;
        const int k = tid >> 5, xo = tid & 31;
        float xv = x[((size_t)b * NT) * 32 + xo];
        float mm = x0_mean[k * 32 + xo];
        float lvv = x0_logvar[k * 32 + xo];
        float dd = xv - mm;
        float term = -0.5f * (dd * dd * __expf(-lvv) + lvv + LOG2PI);
        for (int m = 16; m; m >>= 1) term += __shfl_down(term, m, 32);
        if (xo == 0) log_b[(size_t)b * NT * 8 + k] = term;
        return;
    }
    // ---- log_b, 8 items ----
    float* As = SM;
    float (*xs8)[32] = reinterpret_cast<float(*)[32]>(SM + 8192);
    float (*us8)[2] = reinterpret_cast<float(*)[2]>(SM + 8448);
    const int base = (bid - 1024) * 8;
    for (int i = tid; i < 2048; i += 256)
        reinterpret_cast<float4*>(As)[i] =
            reinterpret_cast<const float4*>(A)[i];
    {
        int row = tid >> 5, xo = tid & 31;
        int item = base + row;
        int b = item / 1023, tm = item - b * 1023;
        xs8[row][xo] = x[((size_t)b * NT + tm) * 32 + xo];
        if (xo < 2) us8[row][xo] = us[((size_t)b * NT + tm + 1) * 2 + xo];
    }
    __syncthreads();
    const int k = tid >> 5, xo = tid & 31;
    const float bxv = bx[k * 32 + xo];
    const float bu0 = Bu[(k * 2 + 0) * 32 + xo];
    const float bu1 = Bu[(k * 2 + 1) * 32 + xo];
    const float lvv = x_logvar[k * 32 + xo];
    const float ivv = __expf(-lvv);
    const float basev = lvv + LOG2PI;
    for (int i = 0; i < 8; ++i) {
        int item = base + i;
        int b = item / 1023, tm = item - b * 1023;
        float acc = fmaf(us8[i][0], bu0, fmaf(us8[i][1], bu1, bxv));
#pragma unroll 8
        for (int e = 0; e < 32; ++e)
            acc = fmaf(xs8[i][e], As[k * 1024 + e * 32 + xo], acc);
        float xv = x[((size_t)b * NT + tm + 1) * 32 + xo];
        float dd = xv - acc;
        float term = dd * dd * ivv + basev;
        for (int m = 16; m; m >>= 1) term += __shfl_down(term, m, 32);
        if (xo == 0)
            log_b[((size_t)b * NT + tm + 1) * 8 + k] = -0.5f * term;
    }
}

// ---------------------------------------------------------------------------
// K5a: chunk products; bexp/max computed inline from log_b.
// ---------------------------------------------------------------------------
__global__ __launch_bounds__(256) void k_fbA(
    const float* __restrict__ ap1, const float* __restrict__ log_b,
    float* __restrict__ Pfx, float* __restrict__ sA)
{
    const int tid = threadIdx.x;
    const int wg = blockIdx.x * 4 + (tid >> 6);
    const int lane = tid & 63;
    const int b = wg / NCH;
    const int c = wg - b * NCH;
    const int j = lane >> 3, k = lane & 7;
    const float* ap = &ap1[(size_t)b * NT * 64];
    const float* lb = &log_b[(size_t)b * NT * 8];
    int t = CHL * c + 1;
    float4 l0 = *reinterpret_cast<const float4*>(&lb[(size_t)t * 8]);
    float4 l1 = *reinterpret_cast<const float4*>(&lb[(size_t)t * 8 + 4]);
    float mm = max8(l0, l1);
    float P = __expf(lb[(size_t)t * 8 + j] - mm) * ap[t * 64 + j * 8 + (j ^ k)];
    float sacc = mm;
    for (int i = 1; i < CHL; ++i) {
        ++t;
        float4 m0 = *reinterpret_cast<const float4*>(&ap[(size_t)t * 64 + j * 8]);
        float4 m1 = *reinterpret_cast<const float4*>(&ap[(size_t)t * 64 + j * 8 + 4]);
        l0 = *reinterpret_cast<const float4*>(&lb[(size_t)t * 8]);
        l1 = *reinterpret_cast<const float4*>(&lb[(size_t)t * 8 + 4]);
        mm = max8(l0, l1);
        float bj = __expf(lb[(size_t)t * 8 + j] - mm);
        sacc += mm;
        float x1 = __shfl_xor(P, 8, 64);
        float x2 = __shfl_xor(P, 16, 64);
        float x3 = __shfl_xor(P, 24, 64);
        float x4 = __shfl_xor(P, 32, 64);
        float x5 = __shfl_xor(P, 40, 64);
        float x6 = __shfl_xor(P, 48, 64);
        float x7 = __shfl_xor(P, 56, 64);
        float c0 = fmaf(m0.y, x1, m0.x * P);
        float c1 = fmaf(m0.w, x3, m0.z * x2);
        float c2 = fmaf(m1.y, x5, m1.x * x4);
        float c3 = fmaf(m1.w, x7, m1.z * x6);
        P = bj * ((c0 + c1) + (c2 + c3));
        if ((i & 3) == 3) {
            float mx = P;
            mx = fmaxf(mx, __shfl_xor(mx, 1, 64));
            mx = fmaxf(mx, __shfl_xor(mx, 2, 64));
            mx = fmaxf(mx, __shfl_xor(mx, 4, 64));
            mx = fmaxf(mx, __shfl_xor(mx, 8, 64));
            mx = fmaxf(mx, __shfl_xor(mx, 16, 64));
            mx = fmaxf(mx, __shfl_xor(mx, 32, 64));
            mx = fmaxf(mx, 1e-30f);
            float r = __builtin_amdgcn_rcpf(mx);
            P *= r;
            sacc -= __logf(r);
        }
    }
    Pfx[((size_t)b * NCH + c) * 64 + j * 8 + (j ^ k)] = P;
    if (lane == 0) sA[b * NCH + c] = sacc;
}

// ---------------------------------------------------------------------------
// K5b: boundary scans over chunk matrices.
// ---------------------------------------------------------------------------
__global__ __launch_bounds__(128) void k_fbB(
    const float* __restrict__ Pfx, const float* __restrict__ sA,
    const float* __restrict__ log_b, const float* __restrict__ log_init_z,
    float* __restrict__ alphaB, float* __restrict__ betaB,
    float* __restrict__ log_px)
{
    const int b = blockIdx.x;
    const int tid = threadIdx.x;
    const int wave = tid >> 6;
    const int lane = tid & 63;
    const int st = lane & 7;
    const float* pf = &Pfx[(size_t)b * NCH * 64];
    if (wave == 0) {
        float liv[8];
        float mz = -1e30f, sz = 0.f;
#pragma unroll
        for (int q = 0; q < 8; ++q) liv[q] = log_init_z[q];
#pragma unroll
        for (int q = 0; q < 8; ++q) mz = fmaxf(mz, liv[q]);
#pragma unroll
        for (int q = 0; q < 8; ++q) sz += __expf(liv[q] - mz);
        const float* lb0 = &log_b[(size_t)b * NT * 8];
        float4 l0 = *reinterpret_cast<const float4*>(lb0);
        float4 l1 = *reinterpret_cast<const float4*>(lb0 + 4);
        float mb0 = max8(l0, l1);
        float alpha = (__expf(liv[st] - mz) / sz) * __expf(lb0[st] - mb0);
        float logS = 0.f, sAsum = 0.f;
        {
            float s = fmaxf(gsum8(alpha), 1e-35f);
            logS += __logf(s);
            alpha *= __builtin_amdgcn_rcpf(s);
        }
        if (lane < 8) alphaB[((size_t)b * (NCH + 1)) * 8 + lane] = alpha;
        for (int c = 0; c < NCH; ++c) {
            float4 a0 = *reinterpret_cast<const float4*>(&pf[(size_t)c * 64 + st * 8]);
            float4 a1 = *reinterpret_cast<const float4*>(&pf[(size_t)c * 64 + st * 8 + 4]);
            alpha = fb_matvec(a0, a1, alpha);
            float s = fmaxf(gsum8(alpha), 1e-35f);
            logS += __logf(s);
            alpha *= __builtin_amdgcn_rcpf(s);
            sAsum += sA[b * NCH + c];
            if (lane < 8) alphaB[((size_t)b * (NCH + 1) + c + 1) * 8 + lane] = alpha;
        }
        if (lane == 0) log_px[b] = mb0 + sAsum + logS;
    } else {
        float beta = 1.f;
        if (lane < 8) betaB[((size_t)b * (NCH + 1) + NCH) * 8 + lane] = 1.f;
        for (int c = NCH - 1; c >= 0; --c) {
            float4 a0 = *reinterpret_cast<const float4*>(&pf[(size_t)c * 64 + st * 8]);
            float4 a1 = *reinterpret_cast<const float4*>(&pf[(size_t)c * 64 + st * 8 + 4]);
            beta = fb_matvecT(a0, a1, beta);
            float s = fmaxf(gsum8(beta), 1e-35f);
            beta *= __builtin_amdgcn_rcpf(s);
            if (lane < 8) betaB[((size_t)b * (NCH + 1) + c) * 8 + lane] = beta;
        }
    }
}

// ---------------------------------------------------------------------------
// K5c: within-chunk recompute + gamma; bexp inline (per-t scale cancels).
// ---------------------------------------------------------------------------
__global__ __launch_bounds__(256) void k_fbC(
    const float* __restrict__ ap1, const float* __restrict__ log_b,
    const float* __restrict__ alphaB, const float* __restrict__ betaB,
    float* __restrict__ gamma)
{
    __shared__ float alphaS[32][CHL][8];
    const int tid = threadIdx.x;
    const int g = tid >> 3;
    const int st = tid & 7;
    const int task = blockIdx.x * 32 + g;
    const int b = task / NCH;
    const int c = task - b * NCH;
    const float* ap = &ap1[(size_t)b * NT * 64];
    const float* lb = &log_b[(size_t)b * NT * 8];
    const int t0 = CHL * c;
    float alpha = alphaB[((size_t)b * (NCH + 1) + c) * 8 + st];
#pragma unroll
    for (int i = 1; i <= CHL; ++i) {
        int t = t0 + i;
        float4 a0 = *reinterpret_cast<const float4*>(&ap[(size_t)t * 64 + st * 8]);
        float4 a1 = *reinterpret_cast<const float4*>(&ap[(size_t)t * 64 + st * 8 + 4]);
        float4 l0 = *reinterpret_cast<const float4*>(&lb[(size_t)t * 8]);
        float4 l1 = *reinterpret_cast<const float4*>(&lb[(size_t)t * 8 + 4]);
        float bv = __expf(lb[(size_t)t * 8 + st] - max8(l0, l1));
        alpha = fb_matvec(a0, a1, alpha) * bv;
        if (i == 5)
            alpha *= __builtin_amdgcn_rcpf(fmaxf(gsum8(alpha), 1e-35f));
        alphaS[g][i - 1][st] = alpha;
    }
    float beta = betaB[((size_t)b * (NCH + 1) + c + 1) * 8 + st];
#pragma unroll
    for (int i = CHL; i >= 1; --i) {
        int t = t0 + i;
        float gv = alphaS[g][i - 1][st] * beta;
        float s = fmaxf(gsum8(gv), 1e-35f);
        gamma[((size_t)b * NT + t) * 8 + st] = gv * __builtin_amdgcn_rcpf(s);
        float4 a0 = *reinterpret_cast<const float4*>(&ap[(size_t)t * 64 + st * 8]);
        float4 a1 = *reinterpret_cast<const float4*>(&ap[(size_t)t * 64 + st * 8 + 4]);
        float4 l0 = *reinterpret_cast<const float4*>(&lb[(size_t)t * 8]);
        float4 l1 = *reinterpret_cast<const float4*>(&lb[(size_t)t * 8 + 4]);
        float bv = __expf(lb[(size_t)t * 8 + st] - max8(l0, l1));
        beta = fb_matvecT(a0, a1, beta * bv);
        if (i == 6)
            beta *= __builtin_amdgcn_rcpf(fmaxf(gsum8(beta), 1e-35f));
    }
    if (c == 0) {
        float a0v = alphaB[((size_t)b * (NCH + 1)) * 8 + st];
        float gv = a0v * beta;
        float s = fmaxf(gsum8(gv), 1e-35f);
        gamma[((size_t)b * NT) * 8 + st] = gv * __builtin_amdgcn_rcpf(s);
    }
}

// ---------------------------------------------------------------------------
// K6: emission via recomputed gamma-mixed mean + factorized quadratic form.
// ---------------------------------------------------------------------------
__global__ __launch_bounds__(256) void k_py(
    const float* __restrict__ x, const float* __restrict__ us,
    const float* __restrict__ A, const float* __restrict__ Bu,
    const float* __restrict__ bx, const float* __restrict__ gamma,
    const float* __restrict__ proj, const float* __restrict__ term1,
    const float* __restrict__ Gm, const float* __restrict__ c2x,
    const float* __restrict__ xent, float* __restrict__ red)
{
    __shared__ float As[8192];
    __shared__ float Gs[32 * 33];
    __shared__ float c2s[32];
    __shared__ float xp8[8][32];
    __shared__ float gs[8][8];
    __shared__ float us8[8][2];
    __shared__ float xgS[8][32];
    const int tid = threadIdx.x;
    const int itemBase = blockIdx.x * 8;
    const int t0 = itemBase & (NT - 1);
    for (int i = tid; i < 2048; i += 256)
        reinterpret_cast<float4*>(As)[i] =
            reinterpret_cast<const float4*>(A)[i];
    for (int i = tid; i < 32 * 33; i += 256) Gs[i] = Gm[i];
    if (tid < 32) c2s[tid] = c2x[tid];
    {
        int it = tid >> 5, xo = tid & 31;
        int t = t0 + it;
        int item = itemBase + it;
        xp8[it][xo] = (t > 0) ? x[((size_t)item - 1) * 32 + xo] : 0.f;
        if (xo < 8) gs[it][xo] = (t > 0) ? gamma[(size_t)item * 8 + xo] : 0.f;
        if (xo < 2) us8[it][xo] = (t > 0) ? us[(size_t)item * 2 + xo] : 0.f;
    }
    __syncthreads();
    const int it = tid >> 5;
    const int xo = tid & 31;
    const int t = t0 + it;
    const int item = itemBase + it;
    float xg;
    if (t == 0) {
        xg = x[(size_t)item * 32 + xo];
    } else {
        xg = 0.f;
#pragma unroll
        for (int k = 0; k < 8; ++k) {
            float acc = bx[k * 32 + xo];
            acc = fmaf(us8[it][0], Bu[(k * 2 + 0) * 32 + xo], acc);
            acc = fmaf(us8[it][1], Bu[(k * 2 + 1) * 32 + xo], acc);
#pragma unroll 8
            for (int e = 0; e < 32; ++e)
                acc = fmaf(xp8[it][e], As[k * 1024 + e * 32 + xo], acc);
            xg = fmaf(gs[it][k], acc, xg);
        }
    }
    xgS[it][xo] = xg;
    __syncthreads();
    float gmv = 0.f;
#pragma unroll 8
    for (int y = 0; y < 32; ++y)
        gmv = fmaf(Gs[xo * 33 + y], xgS[it][y], gmv);
    float val = xg * (proj[(size_t)item * 32 + xo] - c2s[xo] - 0.5f * gmv);
    val += __shfl_xor(val, 1, 64);
    val += __shfl_xor(val, 2, 64);
    val += __shfl_xor(val, 4, 64);
    val += __shfl_xor(val, 8, 64);
    val += __shfl_xor(val, 16, 64);
    if (xo == 0)
        red[item] = -0.5f * term1[item] + val + xent[item];
}

// ---------------------------------------------------------------------------
// K7: elbo = (sum red + sum log_px)/NB - 512*sum(ylv+LOG2PI)
// ---------------------------------------------------------------------------
__global__ __launch_bounds__(256) void k_final(
    const float* __restrict__ red, const float* __restrict__ log_px,
    const float* __restrict__ ylv, float* __restrict__ out)
{
    __shared__ float ssum[4];
    __shared__ float ssum2[4];
    const int tid = threadIdx.x;
    float s = 0.f, t = 0.f;
    for (int i = tid; i < NB * NT; i += 256) s += red[i];
    if (tid < NB) s += log_px[tid];
    for (int i = tid; i < 512; i += 256) t += ylv[i] + LOG2PI;
#pragma unroll
    for (int m = 1; m < 64; m <<= 1) {
        s += __shfl_xor(s, m, 64);
        t += __shfl_xor(t, m, 64);
    }
    if ((tid & 63) == 0) { ssum[tid >> 6] = s; ssum2[tid >> 6] = t; }
    __syncthreads();
    if (tid == 0) {
        float S = ssum[0] + ssum[1] + ssum[2] + ssum[3];
        float T = ssum2[0] + ssum2[1] + ssum2[2] + ssum2[3];
        out[0] = S / (float)NB - 512.0f * T;
    }
}

// ---------------------------------------------------------------------------
extern "C" void kernel_launch(void* const* d_in, const int* in_sizes, int n_in,
                              void* d_out, int out_size, void* d_ws,
                              size_t ws_size, hipStream_t stream)
{
    const float* ys        = (const float*)d_in[0];
    const float* us        = (const float*)d_in[1];
    const float* eps       = (const float*)d_in[2];
    const float* W1        = (const float*)d_in[3];
    const float* b1        = (const float*)d_in[4];
    const float* Wmu       = (const float*)d_in[5];
    const float* bmu       = (const float*)d_in[6];
    const float* Wlv       = (const float*)d_in[7];
    const float* blv       = (const float*)d_in[8];
    const float* Wz        = (const float*)d_in[9];
    const float* bz        = (const float*)d_in[10];
    const float* A         = (const float*)d_in[11];
    const float* Bu        = (const float*)d_in[12];
    const float* bx        = (const float*)d_in[13];
    const float* x_logvar  = (const float*)d_in[14];
    const float* x0_mean   = (const float*)d_in[15];
    const float* x0_logvar = (const float*)d_in[16];
    const float* C         = (const float*)d_in[17];
    const float* dv        = (const float*)d_in[18];
    const float* y_logvar  = (const float*)d_in[19];
    const float* log_init_z= (const float*)d_in[20];
    float* out = (float*)d_out;

    float* ws = (float*)d_ws;
    float* x      = ws;                    //  1,048,576
    float* xent   = x + 1048576;           //     32,768
    float* ap1    = xent + 32768;          //  2,097,152
    float* log_b  = ap1 + 2097152;         //    262,144
    float* gam    = log_b + 262144;        //    262,144
    float* log_px = gam + 262144;          //         32
    float* red    = log_px + 32;           //     32,768
    float* hbf_f  = red + 32768;           //  8,388,608 (h bf16)
    float* w1t_f  = hbf_f + 8388608;       //    131,072 (W1^T bf16)
    float* wmlv_f = w1t_f + 131072;        //     16,384 (Wmu|Wlv^T bf16)
    float* proj   = wmlv_f + 16384;        //  1,048,576
    float* term1  = proj + 1048576;        //     32,768
    float* ivbuf  = term1 + 32768;         //        512
    float* w2bf_f = ivbuf + 512;           //      8,192 (W2 bf16)
    float* Gm     = w2bf_f + 8192;         //      1,056
    float* c2x    = Gm + 1056;             //         32
    float* Pfx    = c2x + 32;              //    190,464
    float* sA     = Pfx + 190464;          //      2,976
    float* alphaB = sA + 2976;             //     24,064
    float* betaB  = alphaB + 24064;        //     24,064

    unsigned short* hbf  = (unsigned short*)hbf_f;
    unsigned short* w1t  = (unsigned short*)w1t_f;
    unsigned short* wmlv = (unsigned short*)wmlv_f;
    unsigned short* w2bf = (unsigned short*)w2bf_f;

    k_prep_w <<<321, 256, 0, stream>>>(W1, Wmu, Wlv, C, dv, y_logvar,
                                       w1t, wmlv, w2bf, Gm, c2x, ivbuf);
    k_gemm_h_mfma<<<dim3(256, 4), 256, 0, stream>>>(ys, w1t, b1, hbf);
    k_proj   <<<256, 256, 0, stream>>>(ys, w2bf, dv, ivbuf, proj, term1);
    k_mulv_mfma<<<256, 256, 0, stream>>>(hbf, wmlv, bmu, blv, eps, x, xent);
    k_lb     <<<5148, 256, 0, stream>>>(x, us, Wz, bz, A, Bu, bx, x_logvar,
                                        x0_mean, x0_logvar, ap1, log_b);
    k_fbA    <<<744, 256, 0, stream>>>(ap1, log_b, Pfx, sA);
    k_fbB    <<<32, 128, 0, stream>>>(Pfx, sA, log_b, log_init_z,
                                      alphaB, betaB, log_px);
    k_fbC    <<<93, 256, 0, stream>>>(ap1, log_b, alphaB, betaB, gam);
    k_py     <<<4096, 256, 0, stream>>>(x, us, A, Bu, bx, gam, proj, term1,
                                        Gm, c2x, xent, red);
    k_final  <<<1, 256, 0, stream>>>(red, log_px, y_logvar, out);
}

// Round 12
// 233.140 us; speedup vs baseline: 1.9891x; 1.0744x over previous
//
#include <hip/hip_runtime.h>
#include <math.h>

#define LOG2PI 1.8378770664093453f

// Problem sizes (fixed)
#define NB 32
#define NT 1024
#define ND 512
#define NH 512
#define NX 32
#define NK 8
#define NU 2

// chunked scan: 1023 transitions = 93 chunks x 11
#define NCH 93
#define CHL 11

typedef __attribute__((ext_vector_type(8))) short bf16x8;
typedef __attribute__((ext_vector_type(4))) float f32x4;

__device__ __forceinline__ unsigned short f2bf(float f) {
    unsigned u = __float_as_uint(f);
    unsigned r = (u + 0x7FFF + ((u >> 16) & 1)) >> 16;
    return (unsigned short)r;
}

// pack two f32 -> two bf16 (round-half-up): 2 adds + 1 v_perm
__device__ __forceinline__ unsigned pack_bf2(float a, float b) {
    unsigned ua = __float_as_uint(a) + 0x8000u;
    unsigned ub = __float_as_uint(b) + 0x8000u;
    return __builtin_amdgcn_perm(ub, ua, 0x07060302);
}

// fast tanh: 1 - 2/(e^{2x}+1)
__device__ __forceinline__ float tanh_fast(float v) {
    float t = __expf(2.0f * v);
    return 1.0f - 2.0f * __builtin_amdgcn_rcpf(t + 1.0f);
}

// ---------------------------------------------------------------------------
// DPP xor-shuffles (VALU pipe, no LDS latency)
// ---------------------------------------------------------------------------
#define DPP_X1 0xB1
#define DPP_X2 0x4E
#define DPP_X3 0x1B
#define DPP_X7 0x141
#define DPP_X15 0x140

template <int CTRL>
__device__ __forceinline__ float dppx(float v) {
    return __int_as_float(__builtin_amdgcn_update_dpp(
        0, __float_as_int(v), CTRL, 0xF, 0xF, true));
}

__device__ __forceinline__ float fb_matvec(float4 a0, float4 a1, float v) {
    float p1 = dppx<DPP_X1>(v);
    float p2 = dppx<DPP_X2>(v);
    float p3 = dppx<DPP_X3>(v);
    float p7 = dppx<DPP_X7>(v);
    float p4 = dppx<DPP_X7>(p3);
    float p5 = dppx<DPP_X7>(p2);
    float p6 = dppx<DPP_X7>(p1);
    float c0 = fmaf(a0.y, p1, a0.x * v);
    float c1 = fmaf(a0.w, p3, a0.z * p2);
    float c2 = fmaf(a1.y, p5, a1.x * p4);
    float c3 = fmaf(a1.w, p7, a1.z * p6);
    return (c0 + c1) + (c2 + c3);
}

__device__ __forceinline__ float fb_matvecT(float4 a0, float4 a1, float w) {
    float q0 = a0.x * w;
    float t1 = dppx<DPP_X1>(a0.y * w);
    float t2 = dppx<DPP_X2>(a0.z * w);
    float t3 = dppx<DPP_X3>(a0.w * w);
    float t7 = dppx<DPP_X7>(a1.w * w);
    float t4 = dppx<DPP_X7>(dppx<DPP_X3>(a1.x * w));
    float t5 = dppx<DPP_X7>(dppx<DPP_X2>(a1.y * w));
    float t6 = dppx<DPP_X7>(dppx<DPP_X1>(a1.z * w));
    return ((q0 + t1) + (t2 + t3)) + ((t4 + t5) + (t6 + t7));
}

__device__ __forceinline__ float gsum8(float v) {
    float s = v + dppx<DPP_X1>(v);
    s = s + dppx<DPP_X2>(s);
    s = s + dppx<DPP_X7>(dppx<DPP_X3>(s));
    return s;
}

// sum over 16-lane group, all-DPP
__device__ __forceinline__ float gsum16(float v) {
    float s = v + dppx<DPP_X1>(v);
    s = s + dppx<DPP_X2>(s);
    s = s + dppx<DPP_X7>(dppx<DPP_X3>(s));
    s = s + dppx<DPP_X15>(dppx<DPP_X7>(s));
    return s;
}

// sum over 32-lane group: 7 DPP + 1 shfl
__device__ __forceinline__ float gsum32(float v) {
    float s = v + dppx<DPP_X1>(v);
    s = s + dppx<DPP_X2>(s);
    s = s + dppx<DPP_X7>(dppx<DPP_X3>(s));
    s = s + dppx<DPP_X15>(dppx<DPP_X7>(s));
    s = s + __shfl_xor(s, 16, 64);
    return s;
}

// max over 8 consecutive floats held as two float4
__device__ __forceinline__ float max8(float4 l0, float4 l1) {
    return fmaxf(fmaxf(fmaxf(l0.x, l0.y), fmaxf(l0.z, l0.w)),
                 fmaxf(fmaxf(l1.x, l1.y), fmaxf(l1.z, l1.w)));
}

// LSE over lanes differing in bits 3..5 (xor 8 via DPP)
__device__ __forceinline__ float lse8_high(float v) {
    float m = v;
    m = fmaxf(m, dppx<DPP_X15>(dppx<DPP_X7>(m)));
    m = fmaxf(m, __shfl_xor(m, 16, 64));
    m = fmaxf(m, __shfl_xor(m, 32, 64));
    float s = __expf(v - m);
    s += dppx<DPP_X15>(dppx<DPP_X7>(s));
    s += __shfl_xor(s, 16, 64);
    s += __shfl_xor(s, 32, 64);
    return m + __logf(s);
}

// ---------------------------------------------------------------------------
// K_prep_w: merged weight prep.
// ---------------------------------------------------------------------------
__global__ __launch_bounds__(256) void k_prep_w(
    const float* __restrict__ W1, const float* __restrict__ Wmu,
    const float* __restrict__ Wlv, const float* __restrict__ C,
    const float* __restrict__ dvec, const float* __restrict__ ylv,
    unsigned short* __restrict__ WT, unsigned short* __restrict__ wmlv,
    unsigned short* __restrict__ W2bf, float* __restrict__ G,
    float* __restrict__ c2x, float* __restrict__ ivbuf)
{
    __shared__ float tile[32][33];
    const int bid = blockIdx.x;
    const int tid = threadIdx.x;
    if (bid < 256) {
        const int bx = (bid & 15) * 32;
        const int by = (bid >> 4) * 32;
        const int tx = tid & 31, ty = tid >> 5;
        for (int i = ty; i < 32; i += 8)
            tile[i][tx] = W1[(size_t)(bx + i) * 512 + by + tx];
        __syncthreads();
        for (int i = ty; i < 32; i += 8)
            WT[(size_t)(by + i) * 512 + bx + tx] = f2bf(tile[tx][i]);
        return;
    }
    if (bid < 288) {
        const int t = bid - 256;
        const float* W = (t >> 4) ? Wlv : Wmu;
        const int base = (t >> 4) * 32;
        const int g = t & 15;
        const int tx = tid & 31, ty = tid >> 5;
        for (int i = ty; i < 32; i += 8)
            tile[i][tx] = W[(size_t)(g * 32 + i) * 32 + tx];
        __syncthreads();
        for (int i = ty; i < 32; i += 8)
            wmlv[(size_t)(base + i) * 512 + g * 32 + tx] = f2bf(tile[tx][i]);
        return;
    }
    if (bid == 320) {
        for (int i = tid; i < 32 * 512; i += 256)
            W2bf[i] = f2bf(C[i] * __expf(-ylv[i & 511]));
        ivbuf[tid] = __expf(-ylv[tid]);
        ivbuf[tid + 256] = __expf(-ylv[tid + 256]);
        return;
    }
    const int x = bid - 288;
    const int y = tid >> 3, seg = tid & 7;
    const float* Cx = &C[(size_t)x * 512];
    const float* Cy = &C[(size_t)y * 512];
    float p = 0.f;
    for (int j = 0; j < 64; ++j) {
        int dcol = seg * 64 + j;
        p = fmaf(Cx[dcol] * __expf(-ylv[dcol]), Cy[dcol], p);
    }
    p = gsum8(p);
    if (seg == 0) G[x * 33 + y] = p;
    if (tid < 8) {
        float q = 0.f;
        for (int j = 0; j < 64; ++j) {
            int dcol = tid * 64 + j;
            q = fmaf(Cx[dcol] * __expf(-ylv[dcol]), dvec[dcol], q);
        }
        q = gsum8(q);
        if (tid == 0) c2x[x] = q;
    }
}

// ---------------------------------------------------------------------------
// K1 (proven): h = bf16(tanh(ys@W1+b1)), 128x128 tile, f32 ys inline-cast.
// ---------------------------------------------------------------------------
__global__ __launch_bounds__(256) void k_gemm_h_mfma(
    const float* __restrict__ ys,
    const unsigned short* __restrict__ Bbf,   // W1T [512][512] bf16
    const float* __restrict__ b1, unsigned short* __restrict__ hb)
{
    __shared__ unsigned short As[128 * 64];
    __shared__ unsigned short Bs[128 * 64];
    const int tid = threadIdx.x;
    const int bm = blockIdx.x * 128;
    const int bn = blockIdx.y * 128;
    const int wid = tid >> 6, lane = tid & 63;
    const int wm = wid >> 1, wn = wid & 1;

    f32x4 acc[4][4];
#pragma unroll
    for (int m = 0; m < 4; ++m)
#pragma unroll
        for (int n = 0; n < 4; ++n)
            acc[m][n] = (f32x4){0.f, 0.f, 0.f, 0.f};

    for (int k0 = 0; k0 < 512; k0 += 64) {
#pragma unroll
        for (int r = 0; r < 4; ++r) {
            int l = tid + r * 256;
            int row = l >> 3, c8 = l & 7;
            int sidx = row * 8 + (c8 ^ (row & 7));
            const float4 f0 = *reinterpret_cast<const float4*>(
                &ys[(size_t)(bm + row) * 512 + k0 + c8 * 8]);
            const float4 f1 = *reinterpret_cast<const float4*>(
                &ys[(size_t)(bm + row) * 512 + k0 + c8 * 8 + 4]);
            uint4 ua;
            ua.x = pack_bf2(f0.x, f0.y);
            ua.y = pack_bf2(f0.z, f0.w);
            ua.z = pack_bf2(f1.x, f1.y);
            ua.w = pack_bf2(f1.z, f1.w);
            *reinterpret_cast<uint4*>(&As[sidx * 8]) = ua;
            uint4 vb = *reinterpret_cast<const uint4*>(
                &Bbf[(size_t)(bn + row) * 512 + k0 + c8 * 8]);
            *reinterpret_cast<uint4*>(&Bs[sidx * 8]) = vb;
        }
        __syncthreads();
#pragma unroll
        for (int kh = 0; kh < 2; ++kh) {
            bf16x8 af[4], bfr[4];
            const int c8r = kh * 4 + (lane >> 4);
#pragma unroll
            for (int m = 0; m < 4; ++m) {
                int rA = wm * 64 + m * 16 + (lane & 15);
                af[m] = *reinterpret_cast<bf16x8*>(
                    &As[rA * 64 + (c8r ^ (rA & 7)) * 8]);
            }
#pragma unroll
            for (int n = 0; n < 4; ++n) {
                int rB = wn * 64 + n * 16 + (lane & 15);
                bfr[n] = *reinterpret_cast<bf16x8*>(
                    &Bs[rB * 64 + (c8r ^ (rB & 7)) * 8]);
            }
#pragma unroll
            for (int m = 0; m < 4; ++m)
#pragma unroll
                for (int n = 0; n < 4; ++n)
                    acc[m][n] = __builtin_amdgcn_mfma_f32_16x16x32_bf16(
                        af[m], bfr[n], acc[m][n], 0, 0, 0);
        }
        __syncthreads();
    }
    float b1v[4];
#pragma unroll
    for (int n = 0; n < 4; ++n)
        b1v[n] = b1[bn + wn * 64 + n * 16 + (lane & 15)];
#pragma unroll
    for (int m = 0; m < 4; ++m) {
#pragma unroll
        for (int q = 0; q < 4; ++q) {
            int row = bm + wm * 64 + m * 16 + (lane >> 4) * 4 + q;
#pragma unroll
            for (int n = 0; n < 4; ++n) {
                int col = bn + wn * 64 + n * 16 + (lane & 15);
                hb[(size_t)row * 512 + col] =
                    f2bf(tanh_fast(acc[m][n][q] + b1v[n]));
            }
        }
    }
}

// ---------------------------------------------------------------------------
// K_pm (merged): blocks 0-255: [mu|lv] GEMM + reparam/xent;
//                blocks 256-511: proj GEMM + term1.
// ---------------------------------------------------------------------------
__global__ __launch_bounds__(256) void k_pm(
    const unsigned short* __restrict__ hbf,
    const unsigned short* __restrict__ Wt,
    const float* __restrict__ bmu, const float* __restrict__ blv,
    const float* __restrict__ eps,
    const float* __restrict__ ys, const unsigned short* __restrict__ W2bf,
    const float* __restrict__ dvec, const float* __restrict__ ivbuf,
    float* __restrict__ x, float* __restrict__ xent,
    float* __restrict__ proj, float* __restrict__ term1)
{
    __shared__ unsigned short SMEM[12288];  // 24 KB
    unsigned short* As = SMEM;
    unsigned short* Bs = SMEM + 8192;
    const int tid = threadIdx.x;
    const int wid = tid >> 6, lane = tid & 63;

    if (blockIdx.x < 256) {
        // ---- mulv ----
        const int bm = blockIdx.x * 128;
        f32x4 acc[2][4];
#pragma unroll
        for (int m = 0; m < 2; ++m)
#pragma unroll
            for (int n = 0; n < 4; ++n)
                acc[m][n] = (f32x4){0.f, 0.f, 0.f, 0.f};

        for (int k0 = 0; k0 < 512; k0 += 64) {
#pragma unroll
            for (int r = 0; r < 4; ++r) {
                int l = tid + r * 256, row = l >> 3, c8 = l & 7;
                int sidx = row * 8 + (c8 ^ (row & 7));
                uint4 v = *reinterpret_cast<const uint4*>(
                    &hbf[(size_t)(bm + row) * 512 + k0 + c8 * 8]);
                *reinterpret_cast<uint4*>(&As[sidx * 8]) = v;
            }
#pragma unroll
            for (int r = 0; r < 2; ++r) {
                int l = tid + r * 256, row = l >> 3, c8 = l & 7;
                int sidx = row * 8 + (c8 ^ (row & 7));
                uint4 v = *reinterpret_cast<const uint4*>(
                    &Wt[(size_t)row * 512 + k0 + c8 * 8]);
                *reinterpret_cast<uint4*>(&Bs[sidx * 8]) = v;
            }
            __syncthreads();
#pragma unroll
            for (int kh = 0; kh < 2; ++kh) {
                const int c8r = kh * 4 + (lane >> 4);
                bf16x8 af[2], bfr[4];
#pragma unroll
                for (int m = 0; m < 2; ++m) {
                    int rA = wid * 32 + m * 16 + (lane & 15);
                    af[m] = *reinterpret_cast<bf16x8*>(
                        &As[rA * 64 + (c8r ^ (rA & 7)) * 8]);
                }
#pragma unroll
                for (int n = 0; n < 4; ++n) {
                    int rB = n * 16 + (lane & 15);
                    bfr[n] = *reinterpret_cast<bf16x8*>(
                        &Bs[rB * 64 + (c8r ^ (rB & 7)) * 8]);
                }
#pragma unroll
                for (int m = 0; m < 2; ++m)
#pragma unroll
                    for (int n = 0; n < 4; ++n)
                        acc[m][n] = __builtin_amdgcn_mfma_f32_16x16x32_bf16(
                            af[m], bfr[n], acc[m][n], 0, 0, 0);
            }
            __syncthreads();
        }
        const int o0 = lane & 15, o1 = 16 + (lane & 15);
        const float bm0 = bmu[o0], bm1 = bmu[o1];
        const float bl0 = blv[o0], bl1 = blv[o1];
#pragma unroll
        for (int m = 0; m < 2; ++m) {
#pragma unroll
            for (int q = 0; q < 4; ++q) {
                int row = bm + wid * 32 + m * 16 + (lane >> 4) * 4 + q;
                float mu0 = acc[m][0][q] + bm0;
                float mu1 = acc[m][1][q] + bm1;
                float lv0 = acc[m][2][q] + bl0;
                float lv1 = acc[m][3][q] + bl1;
                float e0 = eps[(size_t)row * 32 + o0];
                float e1 = eps[(size_t)row * 32 + o1];
                x[(size_t)row * 32 + o0] = mu0 + __expf(0.5f * lv0) * e0;
                x[(size_t)row * 32 + o1] = mu1 + __expf(0.5f * lv1) * e1;
                float pe = (e0 * e0 + lv0) + (e1 * e1 + lv1);
                pe = gsum16(pe);
                if ((lane & 15) == 0)
                    xent[row] = 0.5f * (pe + 32.f * LOG2PI);
            }
        }
        return;
    }
    // ---- proj ----
    const int bm = (blockIdx.x - 256) * 128;
    const int c8 = tid & 7;
    f32x4 acc[2][2];
#pragma unroll
    for (int m = 0; m < 2; ++m)
#pragma unroll
        for (int n = 0; n < 2; ++n)
            acc[m][n] = (f32x4){0.f, 0.f, 0.f, 0.f};
    float t1p[4] = {0.f, 0.f, 0.f, 0.f};

    for (int k0 = 0; k0 < 512; k0 += 64) {
        const float4 dv0 = *reinterpret_cast<const float4*>(&dvec[k0 + c8 * 8]);
        const float4 dv1 = *reinterpret_cast<const float4*>(&dvec[k0 + c8 * 8 + 4]);
        const float4 iv0 = *reinterpret_cast<const float4*>(&ivbuf[k0 + c8 * 8]);
        const float4 iv1 = *reinterpret_cast<const float4*>(&ivbuf[k0 + c8 * 8 + 4]);
#pragma unroll
        for (int r = 0; r < 4; ++r) {
            int l = tid + r * 256;
            int row = l >> 3;
            int sidx = row * 8 + (c8 ^ (row & 7));
            const float4 f0 = *reinterpret_cast<const float4*>(
                &ys[(size_t)(bm + row) * 512 + k0 + c8 * 8]);
            const float4 f1 = *reinterpret_cast<const float4*>(
                &ys[(size_t)(bm + row) * 512 + k0 + c8 * 8 + 4]);
            float g0 = f0.x - dv0.x, g1 = f0.y - dv0.y;
            float g2 = f0.z - dv0.z, g3 = f0.w - dv0.w;
            float g4 = f1.x - dv1.x, g5 = f1.y - dv1.y;
            float g6 = f1.z - dv1.z, g7 = f1.w - dv1.w;
            t1p[r] += (g0 * g0 * iv0.x + g1 * g1 * iv0.y)
                    + (g2 * g2 * iv0.z + g3 * g3 * iv0.w)
                    + (g4 * g4 * iv1.x + g5 * g5 * iv1.y)
                    + (g6 * g6 * iv1.z + g7 * g7 * iv1.w);
            uint4 ua;
            ua.x = pack_bf2(f0.x, f0.y);
            ua.y = pack_bf2(f0.z, f0.w);
            ua.z = pack_bf2(f1.x, f1.y);
            ua.w = pack_bf2(f1.z, f1.w);
            *reinterpret_cast<uint4*>(&As[sidx * 8]) = ua;
        }
        {
            int row = tid >> 3;
            int sidx = row * 8 + (c8 ^ (row & 7));
            uint4 v = *reinterpret_cast<const uint4*>(
                &W2bf[(size_t)row * 512 + k0 + c8 * 8]);
            *reinterpret_cast<uint4*>(&Bs[sidx * 8]) = v;
        }
        __syncthreads();
#pragma unroll
        for (int kh = 0; kh < 2; ++kh) {
            const int c8r = kh * 4 + (lane >> 4);
            bf16x8 af[2], bfr[2];
#pragma unroll
            for (int m = 0; m < 2; ++m) {
                int rA = wid * 32 + m * 16 + (lane & 15);
                af[m] = *reinterpret_cast<bf16x8*>(
                    &As[rA * 64 + (c8r ^ (rA & 7)) * 8]);
            }
#pragma unroll
            for (int n = 0; n < 2; ++n) {
                int rB = n * 16 + (lane & 15);
                bfr[n] = *reinterpret_cast<bf16x8*>(
                    &Bs[rB * 64 + (c8r ^ (rB & 7)) * 8]);
            }
#pragma unroll
            for (int m = 0; m < 2; ++m)
#pragma unroll
                for (int n = 0; n < 2; ++n)
                    acc[m][n] = __builtin_amdgcn_mfma_f32_16x16x32_bf16(
                        af[m], bfr[n], acc[m][n], 0, 0, 0);
        }
        __syncthreads();
    }
#pragma unroll
    for (int m = 0; m < 2; ++m)
#pragma unroll
        for (int q = 0; q < 4; ++q) {
            int row = bm + wid * 32 + m * 16 + (lane >> 4) * 4 + q;
#pragma unroll
            for (int n = 0; n < 2; ++n) {
                int col = n * 16 + (lane & 15);
                proj[(size_t)row * 32 + col] = acc[m][n][q];
            }
        }
#pragma unroll
    for (int r = 0; r < 4; ++r) {
        float s = gsum8(t1p[r]);
        if ((tid & 7) == 0) term1[bm + (tid >> 3) + r * 32] = s;
    }
}

// ---------------------------------------------------------------------------
// K3 (fused): blocks 0-1023: loga; 1024-2046: log_b 32 items/block (2-phase,
// DPP quad reduce); 2047-2078: log_b0.
// ---------------------------------------------------------------------------
__global__ __launch_bounds__(256) void k_lb(
    const float* __restrict__ x, const float* __restrict__ us,
    const float* __restrict__ Wz, const float* __restrict__ bz,
    const float* __restrict__ A, const float* __restrict__ Bu,
    const float* __restrict__ bx, const float* __restrict__ x_logvar,
    const float* __restrict__ x0_mean, const float* __restrict__ x0_logvar,
    float* __restrict__ ap1, float* __restrict__ log_b)
{
    __shared__ float SM[13184];  // 52.7 KB union
    const int tid = threadIdx.x;
    const int bid = blockIdx.x;
    if (bid < 1024) {
        // ---- loga ----
        float (*xs)[32] = reinterpret_cast<float(*)[32]>(SM);
        const int lane = tid & 63;
        const int wv = tid >> 6;
        const int itemBase = bid * 32;
        {
            int r = tid >> 3, cc = (tid & 7) * 4;
            int item = itemBase + r;
            int src = (item & (NT - 1)) ? item - 1 : item;
            *reinterpret_cast<float4*>(&xs[r][cc]) =
                *reinterpret_cast<const float4*>(&x[(size_t)src * 32 + cc]);
        }
        float wcol[32];
#pragma unroll
        for (int e = 0; e < 32; ++e) wcol[e] = Wz[e * 64 + lane];
        const float bzv = bz[lane];
        __syncthreads();
        const int j = lane >> 3, k = lane & 7;
        for (int i = wv; i < 32; i += 4) {
            int item = itemBase + i;
            if ((item & (NT - 1)) == 0) continue;
            float acc = bzv;
#pragma unroll
            for (int e = 0; e < 32; ++e) acc = fmaf(xs[i][e], wcol[e], acc);
            float lse = lse8_high(acc);
            ap1[(size_t)item * 64 + j * 8 + (j ^ k)] = __expf(acc - lse);
        }
        return;
    }
    if (bid >= 2047) {
        // ---- log_b[b][0] ----
        const int b = bid - 2047;
        const int k = tid >> 5, xo = tid & 31;
        float xv = x[((size_t)b * NT) * 32 + xo];
        float mm = x0_mean[k * 32 + xo];
        float lvv = x0_logvar[k * 32 + xo];
        float dd = xv - mm;
        float term = dd * dd * __expf(-lvv) + lvv + LOG2PI;
        term = gsum32(term);
        if (xo == 0) log_b[(size_t)b * NT * 8 + k] = -0.5f * term;
        return;
    }
    // ---- log_b, 32 items, two-phase ----
    float* As = SM;                                              // 8192
    float (*xs)[32] = reinterpret_cast<float(*)[32]>(SM + 8192); // 1024
    float (*xn)[32] = reinterpret_cast<float(*)[32]>(SM + 9216); // 1024
    float (*us2)[2] = reinterpret_cast<float(*)[2]>(SM + 10240); // 64
    float* ivs = SM + 10304;                                     // 288
    float* lvp = SM + 10592;                                     // 288
    float* meanS = SM + 10880;                                   // 2304
    const int base = (bid - 1024) * 32;
    for (int i = tid; i < 2048; i += 256)
        reinterpret_cast<float4*>(As)[i] =
            reinterpret_cast<const float4*>(A)[i];
    {
        int r = tid >> 3, cc = (tid & 7) * 4;
        int item = base + r;
        int b = item / 1023, tm = item - b * 1023;
        *reinterpret_cast<float4*>(&xs[r][cc]) =
            *reinterpret_cast<const float4*>(&x[((size_t)b * NT + tm) * 32 + cc]);
        *reinterpret_cast<float4*>(&xn[r][cc]) =
            *reinterpret_cast<const float4*>(&x[((size_t)b * NT + tm + 1) * 32 + cc]);
    }
    if (tid < 64) {
        int r = tid >> 1, c = tid & 1;
        int item = base + r;
        int b = item / 1023, tm = item - b * 1023;
        us2[r][c] = us[((size_t)b * NT + tm + 1) * 2 + c];
    }
    {
        int k = tid >> 5, xo = tid & 31;
        float lv = x_logvar[k * 32 + xo];
        ivs[k * 36 + xo] = __expf(-lv);
        lvp[k * 36 + xo] = lv + LOG2PI;
    }
    __syncthreads();
    const int k = tid >> 5, xo = tid & 31;       // phase-1 mapping
    const float bxv = bx[k * 32 + xo];
    const float bu0 = Bu[(k * 2 + 0) * 32 + xo];
    const float bu1 = Bu[(k * 2 + 1) * 32 + xo];
    const int i2 = tid >> 5;                     // phase-2 mapping
    const int k2 = (tid >> 2) & 7, q2 = tid & 3;
    for (int g = 0; g < 4; ++g) {
        // phase 1: mean -> LDS
#pragma unroll
        for (int i = 0; i < 8; ++i) {
            int r = g * 8 + i;
            float acc = fmaf(us2[r][0], bu0, fmaf(us2[r][1], bu1, bxv));
#pragma unroll 8
            for (int e = 0; e < 32; ++e)
                acc = fmaf(xs[r][e], As[k * 1024 + e * 32 + xo], acc);
            meanS[(i * 8 + k) * 36 + xo] = acc;
        }
        __syncthreads();
        // phase 2: per-(item,k,quad) partial sums, DPP quad reduce
        {
            int r = g * 8 + i2;
            int item = base + r;
            int b = item / 1023, tm = item - b * 1023;
            const float4 xv0 = *reinterpret_cast<const float4*>(&xn[r][q2 * 8]);
            const float4 xv1 = *reinterpret_cast<const float4*>(&xn[r][q2 * 8 + 4]);
            const float4 m0 = *reinterpret_cast<const float4*>(
                &meanS[(i2 * 8 + k2) * 36 + q2 * 8]);
            const float4 m1 = *reinterpret_cast<const float4*>(
                &meanS[(i2 * 8 + k2) * 36 + q2 * 8 + 4]);
            const float4 v0 = *reinterpret_cast<const float4*>(&ivs[k2 * 36 + q2 * 8]);
            const float4 v1 = *reinterpret_cast<const float4*>(&ivs[k2 * 36 + q2 * 8 + 4]);
            const float4 p0 = *reinterpret_cast<const float4*>(&lvp[k2 * 36 + q2 * 8]);
            const float4 p1 = *reinterpret_cast<const float4*>(&lvp[k2 * 36 + q2 * 8 + 4]);
            float d0 = xv0.x - m0.x, d1 = xv0.y - m0.y;
            float d2 = xv0.z - m0.z, d3 = xv0.w - m0.w;
            float d4 = xv1.x - m1.x, d5 = xv1.y - m1.y;
            float d6 = xv1.z - m1.z, d7 = xv1.w - m1.w;
            float s = ((d0 * d0 * v0.x + p0.x) + (d1 * d1 * v0.y + p0.y))
                    + ((d2 * d2 * v0.z + p0.z) + (d3 * d3 * v0.w + p0.w))
                    + ((d4 * d4 * v1.x + p1.x) + (d5 * d5 * v1.y + p1.y))
                    + ((d6 * d6 * v1.z + p1.z) + (d7 * d7 * v1.w + p1.w));
            s += dppx<DPP_X1>(s);
            s += dppx<DPP_X2>(s);
            if (q2 == 0)
                log_b[((size_t)b * NT + tm + 1) * 8 + k2] = -0.5f * s;
        }
        __syncthreads();
    }
}

// ---------------------------------------------------------------------------
// K5a: chunk products; bexp/max computed inline from log_b.
// ---------------------------------------------------------------------------
__global__ __launch_bounds__(256) void k_fbA(
    const float* __restrict__ ap1, const float* __restrict__ log_b,
    float* __restrict__ Pfx, float* __restrict__ sA)
{
    const int tid = threadIdx.x;
    const int wg = blockIdx.x * 4 + (tid >> 6);
    const int lane = tid & 63;
    const int b = wg / NCH;
    const int c = wg - b * NCH;
    const int j = lane >> 3, k = lane & 7;
    const float* ap = &ap1[(size_t)b * NT * 64];
    const float* lb = &log_b[(size_t)b * NT * 8];
    int t = CHL * c + 1;
    float4 l0 = *reinterpret_cast<const float4*>(&lb[(size_t)t * 8]);
    float4 l1 = *reinterpret_cast<const float4*>(&lb[(size_t)t * 8 + 4]);
    float mm = max8(l0, l1);
    float P = __expf(lb[(size_t)t * 8 + j] - mm) * ap[t * 64 + j * 8 + (j ^ k)];
    float sacc = mm;
    for (int i = 1; i < CHL; ++i) {
        ++t;
        float4 m0 = *reinterpret_cast<const float4*>(&ap[(size_t)t * 64 + j * 8]);
        float4 m1 = *reinterpret_cast<const float4*>(&ap[(size_t)t * 64 + j * 8 + 4]);
        l0 = *reinterpret_cast<const float4*>(&lb[(size_t)t * 8]);
        l1 = *reinterpret_cast<const float4*>(&lb[(size_t)t * 8 + 4]);
        mm = max8(l0, l1);
        float bj = __expf(lb[(size_t)t * 8 + j] - mm);
        sacc += mm;
        float x1 = __shfl_xor(P, 8, 64);
        float x2 = __shfl_xor(P, 16, 64);
        float x3 = __shfl_xor(P, 24, 64);
        float x4 = __shfl_xor(P, 32, 64);
        float x5 = __shfl_xor(P, 40, 64);
        float x6 = __shfl_xor(P, 48, 64);
        float x7 = __shfl_xor(P, 56, 64);
        float c0 = fmaf(m0.y, x1, m0.x * P);
        float c1 = fmaf(m0.w, x3, m0.z * x2);
        float c2 = fmaf(m1.y, x5, m1.x * x4);
        float c3 = fmaf(m1.w, x7, m1.z * x6);
        P = bj * ((c0 + c1) + (c2 + c3));
        if ((i & 3) == 3) {
            float mx = P;
            mx = fmaxf(mx, __shfl_xor(mx, 1, 64));
            mx = fmaxf(mx, __shfl_xor(mx, 2, 64));
            mx = fmaxf(mx, __shfl_xor(mx, 4, 64));
            mx = fmaxf(mx, __shfl_xor(mx, 8, 64));
            mx = fmaxf(mx, __shfl_xor(mx, 16, 64));
            mx = fmaxf(mx, __shfl_xor(mx, 32, 64));
            mx = fmaxf(mx, 1e-30f);
            float r = __builtin_amdgcn_rcpf(mx);
            P *= r;
            sacc -= __logf(r);
        }
    }
    Pfx[((size_t)b * NCH + c) * 64 + j * 8 + (j ^ k)] = P;
    if (lane == 0) sA[b * NCH + c] = sacc;
}

// ---------------------------------------------------------------------------
// K5b: boundary scans over chunk matrices.
// ---------------------------------------------------------------------------
__global__ __launch_bounds__(128) void k_fbB(
    const float* __restrict__ Pfx, const float* __restrict__ sA,
    const float* __restrict__ log_b, const float* __restrict__ log_init_z,
    float* __restrict__ alphaB, float* __restrict__ betaB,
    float* __restrict__ log_px)
{
    const int b = blockIdx.x;
    const int tid = threadIdx.x;
    const int wave = tid >> 6;
    const int lane = tid & 63;
    const int st = lane & 7;
    const float* pf = &Pfx[(size_t)b * NCH * 64];
    if (wave == 0) {
        float liv[8];
        float mz = -1e30f, sz = 0.f;
#pragma unroll
        for (int q = 0; q < 8; ++q) liv[q] = log_init_z[q];
#pragma unroll
        for (int q = 0; q < 8; ++q) mz = fmaxf(mz, liv[q]);
#pragma unroll
        for (int q = 0; q < 8; ++q) sz += __expf(liv[q] - mz);
        const float* lb0 = &log_b[(size_t)b * NT * 8];
        float4 l0 = *reinterpret_cast<const float4*>(lb0);
        float4 l1 = *reinterpret_cast<const float4*>(lb0 + 4);
        float mb0 = max8(l0, l1);
        float alpha = (__expf(liv[st] - mz) / sz) * __expf(lb0[st] - mb0);
        float logS = 0.f, sAsum = 0.f;
        {
            float s = fmaxf(gsum8(alpha), 1e-35f);
            logS += __logf(s);
            alpha *= __builtin_amdgcn_rcpf(s);
        }
        if (lane < 8) alphaB[((size_t)b * (NCH + 1)) * 8 + lane] = alpha;
        for (int c = 0; c < NCH; ++c) {
            float4 a0 = *reinterpret_cast<const float4*>(&pf[(size_t)c * 64 + st * 8]);
            float4 a1 = *reinterpret_cast<const float4*>(&pf[(size_t)c * 64 + st * 8 + 4]);
            alpha = fb_matvec(a0, a1, alpha);
            float s = fmaxf(gsum8(alpha), 1e-35f);
            logS += __logf(s);
            alpha *= __builtin_amdgcn_rcpf(s);
            sAsum += sA[b * NCH + c];
            if (lane < 8) alphaB[((size_t)b * (NCH + 1) + c + 1) * 8 + lane] = alpha;
        }
        if (lane == 0) log_px[b] = mb0 + sAsum + logS;
    } else {
        float beta = 1.f;
        if (lane < 8) betaB[((size_t)b * (NCH + 1) + NCH) * 8 + lane] = 1.f;
        for (int c = NCH - 1; c >= 0; --c) {
            float4 a0 = *reinterpret_cast<const float4*>(&pf[(size_t)c * 64 + st * 8]);
            float4 a1 = *reinterpret_cast<const float4*>(&pf[(size_t)c * 64 + st * 8 + 4]);
            beta = fb_matvecT(a0, a1, beta);
            float s = fmaxf(gsum8(beta), 1e-35f);
            beta *= __builtin_amdgcn_rcpf(s);
            if (lane < 8) betaB[((size_t)b * (NCH + 1) + c) * 8 + lane] = beta;
        }
    }
}

// ---------------------------------------------------------------------------
// K5c: within-chunk recompute + gamma; bexp inline (per-t scale cancels).
// ---------------------------------------------------------------------------
__global__ __launch_bounds__(256) void k_fbC(
    const float* __restrict__ ap1, const float* __restrict__ log_b,
    const float* __restrict__ alphaB, const float* __restrict__ betaB,
    float* __restrict__ gamma)
{
    __shared__ float alphaS[32][CHL][8];
    const int tid = threadIdx.x;
    const int g = tid >> 3;
    const int st = tid & 7;
    const int task = blockIdx.x * 32 + g;
    const int b = task / NCH;
    const int c = task - b * NCH;
    const float* ap = &ap1[(size_t)b * NT * 64];
    const float* lb = &log_b[(size_t)b * NT * 8];
    const int t0 = CHL * c;
    float alpha = alphaB[((size_t)b * (NCH + 1) + c) * 8 + st];
#pragma unroll
    for (int i = 1; i <= CHL; ++i) {
        int t = t0 + i;
        float4 a0 = *reinterpret_cast<const float4*>(&ap[(size_t)t * 64 + st * 8]);
        float4 a1 = *reinterpret_cast<const float4*>(&ap[(size_t)t * 64 + st * 8 + 4]);
        float4 l0 = *reinterpret_cast<const float4*>(&lb[(size_t)t * 8]);
        float4 l1 = *reinterpret_cast<const float4*>(&lb[(size_t)t * 8 + 4]);
        float bv = __expf(lb[(size_t)t * 8 + st] - max8(l0, l1));
        alpha = fb_matvec(a0, a1, alpha) * bv;
        if (i == 5)
            alpha *= __builtin_amdgcn_rcpf(fmaxf(gsum8(alpha), 1e-35f));
        alphaS[g][i - 1][st] = alpha;
    }
    float beta = betaB[((size_t)b * (NCH + 1) + c + 1) * 8 + st];
#pragma unroll
    for (int i = CHL; i >= 1; --i) {
        int t = t0 + i;
        float gv = alphaS[g][i - 1][st] * beta;
        float s = fmaxf(gsum8(gv), 1e-35f);
        gamma[((size_t)b * NT + t) * 8 + st] = gv * __builtin_amdgcn_rcpf(s);
        float4 a0 = *reinterpret_cast<const float4*>(&ap[(size_t)t * 64 + st * 8]);
        float4 a1 = *reinterpret_cast<const float4*>(&ap[(size_t)t * 64 + st * 8 + 4]);
        float4 l0 = *reinterpret_cast<const float4*>(&lb[(size_t)t * 8]);
        float4 l1 = *reinterpret_cast<const float4*>(&lb[(size_t)t * 8 + 4]);
        float bv = __expf(lb[(size_t)t * 8 + st] - max8(l0, l1));
        beta = fb_matvecT(a0, a1, beta * bv);
        if (i == 6)
            beta *= __builtin_amdgcn_rcpf(fmaxf(gsum8(beta), 1e-35f));
    }
    if (c == 0) {
        float a0v = alphaB[((size_t)b * (NCH + 1)) * 8 + st];
        float gv = a0v * beta;
        float s = fmaxf(gsum8(gv), 1e-35f);
        gamma[((size_t)b * NT) * 8 + st] = gv * __builtin_amdgcn_rcpf(s);
    }
}

// ---------------------------------------------------------------------------
// K6: emission, 32 items/block; recomputed gamma-mixed mean + quad form.
// ---------------------------------------------------------------------------
__global__ __launch_bounds__(256) void k_py(
    const float* __restrict__ x, const float* __restrict__ us,
    const float* __restrict__ A, const float* __restrict__ Bu,
    const float* __restrict__ bx, const float* __restrict__ gamma,
    const float* __restrict__ proj, const float* __restrict__ term1,
    const float* __restrict__ Gm, const float* __restrict__ c2x,
    const float* __restrict__ xent, float* __restrict__ red)
{
    __shared__ float As[8192];
    __shared__ float Gs[1056];
    __shared__ float c2s[32];
    __shared__ float xp[32][32];
    __shared__ float gsm[32][8];
    __shared__ float us2[32][2];
    __shared__ float xgS[8 * 36];
    const int tid = threadIdx.x;
    const int itemBase = blockIdx.x * 32;
    const int t0 = itemBase & (NT - 1);
    for (int i = tid; i < 2048; i += 256)
        reinterpret_cast<float4*>(As)[i] =
            reinterpret_cast<const float4*>(A)[i];
    for (int i = tid; i < 1056; i += 256) Gs[i] = Gm[i];
    if (tid < 32) c2s[tid] = c2x[tid];
    {
        int r = tid >> 3, cc = (tid & 7) * 4;
        int item = itemBase + r;
        int src = (t0 + r > 0) ? item - 1 : item;
        *reinterpret_cast<float4*>(&xp[r][cc]) =
            *reinterpret_cast<const float4*>(&x[(size_t)src * 32 + cc]);
    }
    {
        int r = tid >> 3, kk = tid & 7;
        int item = itemBase + r;
        gsm[r][kk] = (t0 + r > 0) ? gamma[(size_t)item * 8 + kk] : 0.f;
    }
    if (tid < 64) {
        int r = tid >> 1, c = tid & 1;
        int item = itemBase + r;
        us2[r][c] = (t0 + r > 0) ? us[(size_t)item * 2 + c] : 0.f;
    }
    __syncthreads();
    const int it = tid >> 5, xo = tid & 31;
    for (int g = 0; g < 4; ++g) {
        const int r = g * 8 + it;
        const int t = t0 + r;
        const int item = itemBase + r;
        float xg;
        if (t == 0) {
            xg = x[(size_t)item * 32 + xo];
        } else {
            xg = 0.f;
#pragma unroll
            for (int kk = 0; kk < 8; ++kk) {
                float acc = bx[kk * 32 + xo];
                acc = fmaf(us2[r][0], Bu[(kk * 2 + 0) * 32 + xo], acc);
                acc = fmaf(us2[r][1], Bu[(kk * 2 + 1) * 32 + xo], acc);
#pragma unroll 8
                for (int e = 0; e < 32; ++e)
                    acc = fmaf(xp[r][e], As[kk * 1024 + e * 32 + xo], acc);
                xg = fmaf(gsm[r][kk], acc, xg);
            }
        }
        xgS[it * 36 + xo] = xg;
        __syncthreads();
        float gmv = 0.f;
#pragma unroll 8
        for (int y = 0; y < 32; ++y)
            gmv = fmaf(Gs[xo * 33 + y], xgS[it * 36 + y], gmv);
        float val = xg * (proj[(size_t)item * 32 + xo] - c2s[xo] - 0.5f * gmv);
        val = gsum32(val);
        if (xo == 0)
            red[item] = -0.5f * term1[item] + val + xent[item];
        __syncthreads();
    }
}

// ---------------------------------------------------------------------------
// K7: elbo = (sum red + sum log_px)/NB - 512*sum(ylv+LOG2PI)
// ---------------------------------------------------------------------------
__global__ __launch_bounds__(256) void k_final(
    const float* __restrict__ red, const float* __restrict__ log_px,
    const float* __restrict__ ylv, float* __restrict__ out)
{
    __shared__ float ssum[4];
    __shared__ float ssum2[4];
    const int tid = threadIdx.x;
    float s = 0.f, t = 0.f;
    for (int i = tid; i < NB * NT; i += 256) s += red[i];
    if (tid < NB) s += log_px[tid];
    for (int i = tid; i < 512; i += 256) t += ylv[i] + LOG2PI;
#pragma unroll
    for (int m = 1; m < 64; m <<= 1) {
        s += __shfl_xor(s, m, 64);
        t += __shfl_xor(t, m, 64);
    }
    if ((tid & 63) == 0) { ssum[tid >> 6] = s; ssum2[tid >> 6] = t; }
    __syncthreads();
    if (tid == 0) {
        float S = ssum[0] + ssum[1] + ssum[2] + ssum[3];
        float T = ssum2[0] + ssum2[1] + ssum2[2] + ssum2[3];
        out[0] = S / (float)NB - 512.0f * T;
    }
}

// ---------------------------------------------------------------------------
extern "C" void kernel_launch(void* const* d_in, const int* in_sizes, int n_in,
                              void* d_out, int out_size, void* d_ws,
                              size_t ws_size, hipStream_t stream)
{
    const float* ys        = (const float*)d_in[0];
    const float* us        = (const float*)d_in[1];
    const float* eps       = (const float*)d_in[2];
    const float* W1        = (const float*)d_in[3];
    const float* b1        = (const float*)d_in[4];
    const float* Wmu       = (const float*)d_in[5];
    const float* bmu       = (const float*)d_in[6];
    const float* Wlv       = (const float*)d_in[7];
    const float* blv       = (const float*)d_in[8];
    const float* Wz        = (const float*)d_in[9];
    const float* bz        = (const float*)d_in[10];
    const float* A         = (const float*)d_in[11];
    const float* Bu        = (const float*)d_in[12];
    const float* bx        = (const float*)d_in[13];
    const float* x_logvar  = (const float*)d_in[14];
    const float* x0_mean   = (const float*)d_in[15];
    const float* x0_logvar = (const float*)d_in[16];
    const float* C         = (const float*)d_in[17];
    const float* dv        = (const float*)d_in[18];
    const float* y_logvar  = (const float*)d_in[19];
    const float* log_init_z= (const float*)d_in[20];
    float* out = (float*)d_out;

    float* ws = (float*)d_ws;
    float* x      = ws;                    //  1,048,576
    float* xent   = x + 1048576;           //     32,768
    float* ap1    = xent + 32768;          //  2,097,152
    float* log_b  = ap1 + 2097152;         //    262,144
    float* gam    = log_b + 262144;        //    262,144
    float* log_px = gam + 262144;          //         32
    float* red    = log_px + 32;           //     32,768
    float* hbf_f  = red + 32768;           //  8,388,608 (h bf16)
    float* w1t_f  = hbf_f + 8388608;       //    131,072 (W1^T bf16)
    float* wmlv_f = w1t_f + 131072;        //     16,384 (Wmu|Wlv^T bf16)
    float* proj   = wmlv_f + 16384;        //  1,048,576
    float* term1  = proj + 1048576;        //     32,768
    float* ivbuf  = term1 + 32768;         //        512
    float* w2bf_f = ivbuf + 512;           //      8,192 (W2 bf16)
    float* Gm     = w2bf_f + 8192;         //      1,056
    float* c2x    = Gm + 1056;             //         32
    float* Pfx    = c2x + 32;              //    190,464
    float* sA     = Pfx + 190464;          //      2,976
    float* alphaB = sA + 2976;             //     24,064
    float* betaB  = alphaB + 24064;        //     24,064

    unsigned short* hbf  = (unsigned short*)hbf_f;
    unsigned short* w1t  = (unsigned short*)w1t_f;
    unsigned short* wmlv = (unsigned short*)wmlv_f;
    unsigned short* w2bf = (unsigned short*)w2bf_f;

    k_prep_w <<<321, 256, 0, stream>>>(W1, Wmu, Wlv, C, dv, y_logvar,
                                       w1t, wmlv, w2bf, Gm, c2x, ivbuf);
    k_gemm_h_mfma<<<dim3(256, 4), 256, 0, stream>>>(ys, w1t, b1, hbf);
    k_pm     <<<512, 256, 0, stream>>>(hbf, wmlv, bmu, blv, eps,
                                       ys, w2bf, dv, ivbuf,
                                       x, xent, proj, term1);
    k_lb     <<<2079, 256, 0, stream>>>(x, us, Wz, bz, A, Bu, bx, x_logvar,
                                        x0_mean, x0_logvar, ap1, log_b);
    k_fbA    <<<744, 256, 0, stream>>>(ap1, log_b, Pfx, sA);
    k_fbB    <<<32, 128, 0, stream>>>(Pfx, sA, log_b, log_init_z,
                                      alphaB, betaB, log_px);
    k_fbC    <<<93, 256, 0, stream>>>(ap1, log_b, alphaB, betaB, gam);
    k_py     <<<1024, 256, 0, stream>>>(x, us, A, Bu, bx, gam, proj, term1,
                                        Gm, c2x, xent, red);
    k_final  <<<1, 256, 0, stream>>>(red, log_px, y_logvar, out);
}